// Round 12
// baseline (160.368 us; speedup 1.0000x reference)
//
#include <hip/hip_runtime.h>
#include <hip/hip_bf16.h>
#include <stdint.h>

// Problem constants (GroupedQueryAttention: B=2,S=2048,D=1024,H=16,KVH=4)
#define B_    2
#define S_    2048
#define D_    1024
#define H_    16
#define KVH_  4
#define HD_   64
#define REP_  4
#define BS_   (B_ * S_)        // 4096 tokens
#define KVD_  256
#define QKVS_ 1536             // fused QKV row stride: Q(1024) | K(256) | V(256)
#define NT_   (S_ / 64)        // 32 KV tiles

typedef unsigned short u16;
typedef short s16x8 __attribute__((ext_vector_type(8)));
typedef float f32x4 __attribute__((ext_vector_type(4)));

typedef const __attribute__((address_space(1))) void* gvp;
typedef __attribute__((address_space(3))) void* lvp;

__device__ __forceinline__ u16 f2b(float f) {  // RNE f32->bf16 (finite inputs)
  uint32_t u = __float_as_uint(f);
  u += 0x7fffu + ((u >> 16) & 1u);
  return (u16)(u >> 16);
}

// XOR swizzle for 64-elem-wide bf16 LDS rows (128B = 8 x 16B slots).
__device__ __forceinline__ int swz64(int row, int slot) {
  return slot ^ (row & 7) ^ ((row >> 3) & 7);
}
__device__ __forceinline__ const s16x8* frag64(const u16* base, int row, int slot) {
  return reinterpret_cast<const s16x8*>(base + row * 64 + swz64(row, slot) * 8);
}

// ---------------- fused f32 -> bf16 conversion over 5 segments ----------------
#define N0_ (BS_ * D_ / 4)
#define N1_ (D_ * D_ / 4)
#define N2_ (KVD_ * D_ / 4)
__global__ void cvt5_kernel(const float* __restrict__ s0, const float* __restrict__ s1,
                            const float* __restrict__ s2, const float* __restrict__ s3,
                            const float* __restrict__ s4, u16* __restrict__ dst, int n4tot) {
  for (int i = blockIdx.x * blockDim.x + threadIdx.x; i < n4tot;
       i += gridDim.x * blockDim.x) {
    const float* src;
    int j = i;
    if (j < N0_) src = s0;
    else if ((j -= N0_) < N1_) src = s1;
    else if ((j -= N1_) < N2_) src = s2;
    else if ((j -= N2_) < N2_) src = s3;
    else { j -= N2_; src = s4; }
    const float4 v = reinterpret_cast<const float4*>(src)[j];
    uint2 o;
    o.x = (uint32_t)f2b(v.x) | ((uint32_t)f2b(v.y) << 16);
    o.y = (uint32_t)f2b(v.z) | ((uint32_t)f2b(v.w) << 16);
    reinterpret_cast<uint2*>(dst)[i] = o;
  }
}

// ---------------- bf16 GEMM, C = A(MxK) * B(NxK)^T, 64x128 tile ----------------
template <int OUT_BF16>
__global__ __launch_bounds__(256) void gemm64(const u16* __restrict__ A,
                                              const u16* __restrict__ Bw,
                                              void* __restrict__ Cout,
                                              int M, int N, int K) {
  __shared__ u16 As[64 * 32];
  __shared__ u16 Bs[128 * 32];
  const int tid = threadIdx.x;
  const int lane = tid & 63;
  const int wid = tid >> 6;
  const int l16 = lane & 15;
  const int kq = lane >> 4;
  const int bm = blockIdx.y * 64;
  const int bn = blockIdx.x * 128;
  const int wr = (wid >> 1) * 32;
  const int wc = (wid & 1) * 64;

  f32x4 acc[2][4] = {};

  for (int kt = 0; kt < K; kt += 32) {
    __syncthreads();
    {  // A tile: 64x32, 1 load/thread
      const int e = tid * 8;
      const int row = e >> 5;
      const int col = e & 31;
      __builtin_amdgcn_global_load_lds((gvp)(A + (size_t)(bm + row) * K + kt + col),
                                       (lvp)(&As[e]), 16, 0, 0);
    }
#pragma unroll
    for (int i = 0; i < 2; ++i) {  // B tile: 128x32, 2 loads/thread
      const int e = (i * 256 + tid) * 8;
      const int row = e >> 5;
      const int col = e & 31;
      __builtin_amdgcn_global_load_lds((gvp)(Bw + (size_t)(bn + row) * K + kt + col),
                                       (lvp)(&Bs[e]), 16, 0, 0);
    }
    __syncthreads();

    s16x8 af[2], bfr[4];
#pragma unroll
    for (int m = 0; m < 2; ++m)
      af[m] = *reinterpret_cast<const s16x8*>(&As[(wr + m * 16 + l16) * 32 + kq * 8]);
#pragma unroll
    for (int n = 0; n < 4; ++n)
      bfr[n] = *reinterpret_cast<const s16x8*>(&Bs[(wc + n * 16 + l16) * 32 + kq * 8]);
#pragma unroll
    for (int m = 0; m < 2; ++m)
#pragma unroll
      for (int n = 0; n < 4; ++n)
        acc[m][n] = __builtin_amdgcn_mfma_f32_16x16x32_bf16(af[m], bfr[n], acc[m][n], 0, 0, 0);
  }

#pragma unroll
  for (int m = 0; m < 2; ++m) {
    const int row0 = bm + wr + m * 16 + kq * 4;
#pragma unroll
    for (int n = 0; n < 4; ++n) {
      const int col = bn + wc + n * 16 + l16;
#pragma unroll
      for (int r = 0; r < 4; ++r) {
        if (OUT_BF16) {
          ((u16*)Cout)[(size_t)(row0 + r) * N + col] = f2b(acc[m][n][r]);
        } else {
          ((float*)Cout)[(size_t)(row0 + r) * N + col] = acc[m][n][r];
        }
      }
    }
  }
}

// ---------------- V transpose: QKV V-part -> VT[(b*4+g)*64 + d][s] ----------------
__global__ __launch_bounds__(256) void vtrans_kernel(const u16* __restrict__ QKV,
                                                     u16* __restrict__ VT) {
  __shared__ u16 T[64][72];
  const int tid = threadIdx.x;
  const int s0 = blockIdx.x * 64;
  const int bg = blockIdx.y;
  const int b = bg >> 2;
  const int g = bg & 3;
  const int r = tid >> 2;
  const int c0 = (tid & 3) * 16;
  const u16* src = QKV + (size_t)(b * S_ + s0 + r) * QKVS_ + D_ + KVD_ + g * HD_ + c0;
  const uint4 a = reinterpret_cast<const uint4*>(src)[0];
  const uint4 bq = reinterpret_cast<const uint4*>(src)[1];
  *reinterpret_cast<uint4*>(&T[r][c0]) = a;
  *reinterpret_cast<uint4*>(&T[r][c0 + 8]) = bq;
  __syncthreads();
  const int d = tid >> 2;
  u16 tmp[16];
#pragma unroll
  for (int j = 0; j < 16; ++j) tmp[j] = T[c0 + j][d];
  u16* dst = VT + ((size_t)bg * 64 + d) * S_ + s0 + c0;
  *reinterpret_cast<uint4*>(dst) = *reinterpret_cast<const uint4*>(&tmp[0]);
  *reinterpret_cast<uint4*>(dst + 8) = *reinterpret_cast<const uint4*>(&tmp[8]);
}

// ---------------- flash attention (GQA): swapped-QK^T, 32 q-rows/wave ----------------
// Round-10 verified structure + raw-domain softmax + ballot mask (no smask LDS).
__global__ __launch_bounds__(256) void attn_kernel(const u16* __restrict__ QKV,
                                                   const u16* __restrict__ VT,
                                                   const int* __restrict__ mask,
                                                   u16* __restrict__ O) {
  __shared__ u16 Ks[2][64 * 64];
  __shared__ u16 Vt[2][64 * 64];       // Vt[d][kv], slot-swizzled

  const int tid = threadIdx.x;
  const int lane = tid & 63;
  const int wid = tid >> 6;            // 0..3 = head within group
  const int l16 = lane & 15;
  const int kq = lane >> 4;            // 0..3
  const int bg = blockIdx.y;
  const int b = bg >> 2;               // / KVH
  const int g = bg & 3;
  const int h = g * REP_ + wid;
  const int q0 = blockIdx.x * 32;
  const u16* kv_base = QKV + (size_t)b * S_ * QKVS_ + D_ + g * HD_;  // K cols
  const u16* vt_base = VT + (size_t)bg * 64 * S_;                     // V^T rows
  const float Cs = 0.18033688011112042f;  // SCALE * log2(e)

  auto kstage = [&](int buf, int kv0) {
#pragma unroll
    for (int i = 0; i < 2; ++i) {
      const int e = (i * 256 + tid) * 8;
      const int row = e >> 6;
      const int slot = (e >> 3) & 7;
      __builtin_amdgcn_global_load_lds(
          (gvp)(kv_base + (size_t)(kv0 + row) * QKVS_ + swz64(row, slot) * 8),
          (lvp)(&Ks[buf][e]), 16, 0, 0);
    }
  };
  auto vstage = [&](int buf, int kv0) {
#pragma unroll
    for (int i = 0; i < 2; ++i) {
      const int e = (i * 256 + tid) * 8;
      const int row = e >> 6;          // d
      const int slot = (e >> 3) & 7;
      __builtin_amdgcn_global_load_lds(
          (gvp)(vt_base + (size_t)row * S_ + kv0 + swz64(row, slot) * 8),
          (lvp)(&Vt[buf][e]), 16, 0, 0);
    }
  };

  // Q B-frags: qf[g2][c] = Q[q0+g2*16+l16][c*32+kq*8..], group g2 in {0,1}
  s16x8 qf[2][2];
#pragma unroll
  for (int g2 = 0; g2 < 2; ++g2) {
    const u16* qp = QKV + (size_t)(b * S_ + q0 + g2 * 16 + l16) * QKVS_ + h * HD_ + kq * 8;
    qf[g2][0] = *reinterpret_cast<const s16x8*>(qp);
    qf[g2][1] = *reinterpret_cast<const s16x8*>(qp + 32);
  }

  // prologue: stage tile 0 into buf 0; mask for tile 0 into regs
  kstage(0, 0);
  vstage(0, 0);
  int mcur = mask[b * S_ + lane];

  float m_run[2] = {-1e30f, -1e30f}, l_run[2] = {0.f, 0.f};
  f32x4 acc[2][4] = {};                // O^T per group: row d=m*16+kq*4+r, col q=l16
  int cur = 0;

  for (int t = 0; t < NT_; ++t) {
    __syncthreads();                   // buf[cur] ready; buf[cur^1] free
    const bool pfch = (t + 1 < NT_);
    int mnext = 0;
    if (pfch) {
      kstage(cur ^ 1, (t + 1) * 64);   // direct-to-LDS, stays in flight
      vstage(cur ^ 1, (t + 1) * 64);
      mnext = mask[b * S_ + (t + 1) * 64 + lane];
    }

    const u16* ks = &Ks[cur][0];
    const u16* vt = &Vt[cur][0];

    // mask bits for this tile (uniform across wave); fast path = all valid
    const unsigned long long mbits = __ballot(mcur != 0);
    const bool needmask = (~mbits) != 0ull;
    uint32_t nib[4];
    if (needmask) {
#pragma unroll
      for (int n = 0; n < 4; ++n)
        nib[n] = (uint32_t)(mbits >> (n * 16 + kq * 4)) & 0xFu;
    }

    // S^T = K·Q^T (raw scores) for both q-groups; K frag read shared
    f32x4 sc[2][4];
#pragma unroll
    for (int n = 0; n < 4; ++n) {
      f32x4 s0 = {0.f, 0.f, 0.f, 0.f};
      f32x4 s1 = {0.f, 0.f, 0.f, 0.f};
#pragma unroll
      for (int c = 0; c < 2; ++c) {
        const s16x8 kf = *frag64(ks, n * 16 + l16, c * 4 + kq);
        s0 = __builtin_amdgcn_mfma_f32_16x16x32_bf16(kf, qf[0][c], s0, 0, 0, 0);
        s1 = __builtin_amdgcn_mfma_f32_16x16x32_bf16(kf, qf[1][c], s1, 0, 0, 0);
      }
      sc[0][n] = s0;
      sc[1][n] = s1;
    }

    union { uint32_t u[4]; s16x8 v; } pf[2][2];
#pragma unroll
    for (int g2 = 0; g2 < 2; ++g2) {
      // raw-domain row max (16 local + 2 shfl across kq)
      float tm = -1e30f;
#pragma unroll
      for (int n = 0; n < 4; ++n)
#pragma unroll
        for (int r = 0; r < 4; ++r) tm = fmaxf(tm, sc[g2][n][r]);
      tm = fmaxf(tm, __shfl_xor(tm, 16));
      tm = fmaxf(tm, __shfl_xor(tm, 32));

      // defer-rescale (T13), raw domain: 44 raw ~= 8 exp2-units
      if (!__all(tm <= m_run[g2] + 44.0f)) {
        const float mnew = fmaxf(m_run[g2], tm);
        const float fac = exp2f((m_run[g2] - mnew) * Cs);
        m_run[g2] = mnew;
        l_run[g2] *= fac;
#pragma unroll
        for (int m = 0; m < 4; ++m)
#pragma unroll
          for (int r = 0; r < 4; ++r) acc[g2][m][r] *= fac;
      }

      // exp2 in scaled domain; zero masked P after exp (max over superset ok)
      float rs = 0.f;
      const float mneg = -m_run[g2] * Cs;
#pragma unroll
      for (int n = 0; n < 4; ++n)
#pragma unroll
        for (int r = 0; r < 4; ++r) {
          float p = exp2f(fmaf(sc[g2][n][r], Cs, mneg));
          if (needmask) p = ((nib[n] >> r) & 1u) ? p : 0.f;
          sc[g2][n][r] = p;
          rs += p;
        }
      rs += __shfl_xor(rs, 16);
      rs += __shfl_xor(rs, 32);
      l_run[g2] += rs;

      // pack P to bf16 pairs
      uint32_t pk[4][2];
#pragma unroll
      for (int n = 0; n < 4; ++n) {
        asm("v_cvt_pk_bf16_f32 %0, %1, %2" : "=v"(pk[n][0]) : "v"(sc[g2][n][0]), "v"(sc[g2][n][1]));
        asm("v_cvt_pk_bf16_f32 %0, %1, %2" : "=v"(pk[n][1]) : "v"(sc[g2][n][2]), "v"(sc[g2][n][3]));
      }
      // exchange: frag c word w <- pk[2c+(kq>>1)][w&1] of lane ((kq&1)*2+(w>>1))*16+l16
      const int srcA = ((kq & 1) * 2) * 16 + l16;
      const int srcB = srcA + 16;
#pragma unroll
      for (int c = 0; c < 2; ++c)
#pragma unroll
        for (int w = 0; w < 4; ++w) {
          const int src = (w < 2) ? srcA : srcB;
          const uint32_t lo = __shfl(pk[2 * c][w & 1], src);
          const uint32_t hi = __shfl(pk[2 * c + 1][w & 1], src);
          pf[g2][c].u[w] = (kq & 2) ? hi : lo;
        }
    }

    // O^T += V^T·P^T; V frag read shared by both groups
#pragma unroll
    for (int m = 0; m < 4; ++m) {
      const s16x8 vf0 = *frag64(vt, m * 16 + l16, kq);
      const s16x8 vf1 = *frag64(vt, m * 16 + l16, 4 + kq);
      acc[0][m] = __builtin_amdgcn_mfma_f32_16x16x32_bf16(vf0, pf[0][0].v, acc[0][m], 0, 0, 0);
      acc[0][m] = __builtin_amdgcn_mfma_f32_16x16x32_bf16(vf1, pf[0][1].v, acc[0][m], 0, 0, 0);
      acc[1][m] = __builtin_amdgcn_mfma_f32_16x16x32_bf16(vf0, pf[1][0].v, acc[1][m], 0, 0, 0);
      acc[1][m] = __builtin_amdgcn_mfma_f32_16x16x32_bf16(vf1, pf[1][1].v, acc[1][m], 0, 0, 0);
    }

    mcur = mnext;
    cur ^= 1;
  }

  // normalize + store O^T -> O (bf16, token-major [BS][D])
#pragma unroll
  for (int g2 = 0; g2 < 2; ++g2) {
    const float rl = 1.0f / l_run[g2];
    u16* op = O + (size_t)(b * S_ + q0 + g2 * 16 + l16) * D_ + h * HD_ + kq * 4;
#pragma unroll
    for (int m = 0; m < 4; ++m) {
      uint2 o;
      o.x = (uint32_t)f2b(acc[g2][m][0] * rl) | ((uint32_t)f2b(acc[g2][m][1] * rl) << 16);
      o.y = (uint32_t)f2b(acc[g2][m][2] * rl) | ((uint32_t)f2b(acc[g2][m][3] * rl) << 16);
      *reinterpret_cast<uint2*>(op + m * 16) = o;
    }
  }
}

// ---------------- launch ----------------
extern "C" void kernel_launch(void* const* d_in, const int* in_sizes, int n_in,
                              void* d_out, int out_size, void* d_ws, size_t ws_size,
                              hipStream_t stream) {
  const float* x = (const float*)d_in[0];
  const int* mask = (const int*)d_in[1];
  const float* Wq = (const float*)d_in[2];
  const float* Wk = (const float*)d_in[3];
  const float* Wv = (const float*)d_in[4];
  const float* Wo = (const float*)d_in[5];

  char* w = (char*)d_ws;
  u16* xb = (u16*)w;    w += (size_t)BS_ * D_ * 2;     // contiguous cvt dst
  u16* Wqkvb = (u16*)w; w += (size_t)QKVS_ * D_ * 2;
  u16* Wob = (u16*)w;   w += (size_t)D_ * D_ * 2;
  u16* QKVw = (u16*)w;  w += (size_t)BS_ * QKVS_ * 2;
  u16* VTw = (u16*)w;   w += (size_t)B_ * KVH_ * HD_ * S_ * 2;
  u16* AOw = (u16*)w;   w += (size_t)BS_ * D_ * 2;

  const int n4tot = (BS_ * D_ + QKVS_ * D_ + D_ * D_) / 4;
  cvt5_kernel<<<dim3(2048), dim3(256), 0, stream>>>(x, Wq, Wk, Wv, Wo, xb, n4tot);

  // fused QKV projection: (4096 x 1536), 64x128 tiles -> 768 blocks (3/CU)
  gemm64<1><<<dim3(QKVS_ / 128, BS_ / 64), dim3(256), 0, stream>>>(xb, Wqkvb, QKVw, BS_, QKVS_, D_);
  // transpose V for direct LDS staging
  vtrans_kernel<<<dim3(S_ / 64, B_ * KVH_), dim3(256), 0, stream>>>(QKVw, VTw);
  // attention: (S/32, B*KVH) blocks of 4 waves, 32 q-rows/wave
  attn_kernel<<<dim3(S_ / 32, B_ * KVH_), dim3(256), 0, stream>>>(QKVw, VTw, mask, AOw);
  // output projection -> fp32 d_out, 64x128 tiles -> 512 blocks (2/CU)
  gemm64<0><<<dim3(D_ / 128, BS_ / 64), dim3(256), 0, stream>>>(AOw, Wob, (float*)d_out, BS_, D_, D_);
}

// Round 14
// 139.621 us; speedup vs baseline: 1.1486x; 1.1486x over previous
//
#include <hip/hip_runtime.h>
#include <hip/hip_bf16.h>
#include <stdint.h>

// Problem constants (GroupedQueryAttention: B=2,S=2048,D=1024,H=16,KVH=4)
#define B_    2
#define S_    2048
#define D_    1024
#define H_    16
#define KVH_  4
#define HD_   64
#define REP_  4
#define BS_   (B_ * S_)        // 4096 tokens
#define KVD_  256
#define QKVS_ 1536             // fused QKV row stride: Q(1024) | K(256) | V(256)
#define NT_   (S_ / 64)        // 32 KV tiles

typedef unsigned short u16;
typedef short s16x4 __attribute__((ext_vector_type(4)));
typedef short s16x8 __attribute__((ext_vector_type(8)));
typedef float f32x4 __attribute__((ext_vector_type(4)));

typedef const __attribute__((address_space(1))) void* gvp;
typedef __attribute__((address_space(3))) void* lvp;

__device__ __forceinline__ u16 f2b(float f) {  // RNE f32->bf16 (finite inputs)
  uint32_t u = __float_as_uint(f);
  u += 0x7fffu + ((u >> 16) & 1u);
  return (u16)(u >> 16);
}

// XOR swizzle for 64-elem-wide bf16 LDS rows (128B = 8 x 16B slots).
__device__ __forceinline__ int swz64(int row, int slot) {
  return slot ^ (row & 7) ^ ((row >> 3) & 7);
}
__device__ __forceinline__ const s16x8* frag64(const u16* base, int row, int slot) {
  return reinterpret_cast<const s16x8*>(base + row * 64 + swz64(row, slot) * 8);
}

// ---------------- fused f32 -> bf16 conversion over 5 segments ----------------
#define N0_ (BS_ * D_ / 4)
#define N1_ (D_ * D_ / 4)
#define N2_ (KVD_ * D_ / 4)
__global__ void cvt5_kernel(const float* __restrict__ s0, const float* __restrict__ s1,
                            const float* __restrict__ s2, const float* __restrict__ s3,
                            const float* __restrict__ s4, u16* __restrict__ dst, int n4tot) {
  for (int i = blockIdx.x * blockDim.x + threadIdx.x; i < n4tot;
       i += gridDim.x * blockDim.x) {
    const float* src;
    int j = i;
    if (j < N0_) src = s0;
    else if ((j -= N0_) < N1_) src = s1;
    else if ((j -= N1_) < N2_) src = s2;
    else if ((j -= N2_) < N2_) src = s3;
    else { j -= N2_; src = s4; }
    const float4 v = reinterpret_cast<const float4*>(src)[j];
    uint2 o;
    o.x = (uint32_t)f2b(v.x) | ((uint32_t)f2b(v.y) << 16);
    o.y = (uint32_t)f2b(v.z) | ((uint32_t)f2b(v.w) << 16);
    reinterpret_cast<uint2*>(dst)[i] = o;
  }
}

// ---------------- bf16 GEMM, C = A(MxK) * B(NxK)^T, 64x128 tile ----------------
template <int OUT_BF16>
__global__ __launch_bounds__(256) void gemm64(const u16* __restrict__ A,
                                              const u16* __restrict__ Bw,
                                              void* __restrict__ Cout,
                                              int M, int N, int K) {
  __shared__ u16 As[64 * 32];
  __shared__ u16 Bs[128 * 32];
  const int tid = threadIdx.x;
  const int lane = tid & 63;
  const int wid = tid >> 6;
  const int l16 = lane & 15;
  const int kq = lane >> 4;
  const int bm = blockIdx.y * 64;
  const int bn = blockIdx.x * 128;
  const int wr = (wid >> 1) * 32;
  const int wc = (wid & 1) * 64;

  f32x4 acc[2][4] = {};

  for (int kt = 0; kt < K; kt += 32) {
    __syncthreads();
    {  // A tile: 64x32, 1 load/thread
      const int e = tid * 8;
      const int row = e >> 5;
      const int col = e & 31;
      __builtin_amdgcn_global_load_lds((gvp)(A + (size_t)(bm + row) * K + kt + col),
                                       (lvp)(&As[e]), 16, 0, 0);
    }
#pragma unroll
    for (int i = 0; i < 2; ++i) {  // B tile: 128x32, 2 loads/thread
      const int e = (i * 256 + tid) * 8;
      const int row = e >> 5;
      const int col = e & 31;
      __builtin_amdgcn_global_load_lds((gvp)(Bw + (size_t)(bn + row) * K + kt + col),
                                       (lvp)(&Bs[e]), 16, 0, 0);
    }
    __syncthreads();

    s16x8 af[2], bfr[4];
#pragma unroll
    for (int m = 0; m < 2; ++m)
      af[m] = *reinterpret_cast<const s16x8*>(&As[(wr + m * 16 + l16) * 32 + kq * 8]);
#pragma unroll
    for (int n = 0; n < 4; ++n)
      bfr[n] = *reinterpret_cast<const s16x8*>(&Bs[(wc + n * 16 + l16) * 32 + kq * 8]);
#pragma unroll
    for (int m = 0; m < 2; ++m)
#pragma unroll
      for (int n = 0; n < 4; ++n)
        acc[m][n] = __builtin_amdgcn_mfma_f32_16x16x32_bf16(af[m], bfr[n], acc[m][n], 0, 0, 0);
  }

#pragma unroll
  for (int m = 0; m < 2; ++m) {
    const int row0 = bm + wr + m * 16 + kq * 4;
#pragma unroll
    for (int n = 0; n < 4; ++n) {
      const int col = bn + wc + n * 16 + l16;
#pragma unroll
      for (int r = 0; r < 4; ++r) {
        if (OUT_BF16) {
          ((u16*)Cout)[(size_t)(row0 + r) * N + col] = f2b(acc[m][n][r]);
        } else {
          ((float*)Cout)[(size_t)(row0 + r) * N + col] = acc[m][n][r];
        }
      }
    }
  }
}

// ---------------- V transpose: QKV V-part -> VT[(b*4+g)*64 + d][s] ----------------
__global__ __launch_bounds__(256) void vtrans_kernel(const u16* __restrict__ QKV,
                                                     u16* __restrict__ VT) {
  __shared__ u16 T[64][72];
  const int tid = threadIdx.x;
  const int s0 = blockIdx.x * 64;
  const int bg = blockIdx.y;
  const int b = bg >> 2;
  const int g = bg & 3;
  const int r = tid >> 2;
  const int c0 = (tid & 3) * 16;
  const u16* src = QKV + (size_t)(b * S_ + s0 + r) * QKVS_ + D_ + KVD_ + g * HD_ + c0;
  const uint4 a = reinterpret_cast<const uint4*>(src)[0];
  const uint4 bq = reinterpret_cast<const uint4*>(src)[1];
  *reinterpret_cast<uint4*>(&T[r][c0]) = a;
  *reinterpret_cast<uint4*>(&T[r][c0 + 8]) = bq;
  __syncthreads();
  const int d = tid >> 2;
  u16 tmp[16];
#pragma unroll
  for (int j = 0; j < 16; ++j) tmp[j] = T[c0 + j][d];
  u16* dst = VT + ((size_t)bg * 64 + d) * S_ + s0 + c0;
  *reinterpret_cast<uint4*>(dst) = *reinterpret_cast<const uint4*>(&tmp[0]);
  *reinterpret_cast<uint4*>(dst + 8) = *reinterpret_cast<const uint4*>(&tmp[8]);
}

// ---------------- flash attention (GQA): swapped-QK^T, zero-shuffle PV ----------------
// P stays in registers: lane (kq,l16)'s C-layout pk pairs ARE the PV B-frag
// under the k-axis permutation pi(k): k=8kq+j -> kv=32c+16(j>>2)+4kq+(j&3).
// V (A operand) absorbs pi by reading two b64 chunks per frag:
// V^T[d][32c+4kq..+3] and V^T[d][32c+16+4kq..+3]. No bpermute, no selects.
__global__ __launch_bounds__(256) void attn_kernel(const u16* __restrict__ QKV,
                                                   const u16* __restrict__ VT,
                                                   const int* __restrict__ mask,
                                                   u16* __restrict__ O) {
  __shared__ u16 Ks[2][64 * 64];
  __shared__ u16 Vt[2][64 * 64];       // Vt[d][kv], slot-swizzled

  const int tid = threadIdx.x;
  const int lane = tid & 63;
  const int wid = tid >> 6;            // 0..3 = head within group
  const int l16 = lane & 15;
  const int kq = lane >> 4;            // 0..3
  const int bg = blockIdx.y;
  const int b = bg >> 2;               // / KVH
  const int g = bg & 3;
  const int h = g * REP_ + wid;
  const int q0 = blockIdx.x * 32;
  const u16* kv_base = QKV + (size_t)b * S_ * QKVS_ + D_ + g * HD_;  // K cols
  const u16* vt_base = VT + (size_t)bg * 64 * S_;                     // V^T rows
  const float Cs = 0.18033688011112042f;  // SCALE * log2(e)

  auto kstage = [&](int buf, int kv0) {
#pragma unroll
    for (int i = 0; i < 2; ++i) {
      const int e = (i * 256 + tid) * 8;
      const int row = e >> 6;
      const int slot = (e >> 3) & 7;
      __builtin_amdgcn_global_load_lds(
          (gvp)(kv_base + (size_t)(kv0 + row) * QKVS_ + swz64(row, slot) * 8),
          (lvp)(&Ks[buf][e]), 16, 0, 0);
    }
  };
  auto vstage = [&](int buf, int kv0) {
#pragma unroll
    for (int i = 0; i < 2; ++i) {
      const int e = (i * 256 + tid) * 8;
      const int row = e >> 6;          // d
      const int slot = (e >> 3) & 7;
      __builtin_amdgcn_global_load_lds(
          (gvp)(vt_base + (size_t)row * S_ + kv0 + swz64(row, slot) * 8),
          (lvp)(&Vt[buf][e]), 16, 0, 0);
    }
  };

  // Q B-frags: qf[g2][c] = Q[q0+g2*16+l16][c*32+kq*8..], group g2 in {0,1}
  s16x8 qf[2][2];
#pragma unroll
  for (int g2 = 0; g2 < 2; ++g2) {
    const u16* qp = QKV + (size_t)(b * S_ + q0 + g2 * 16 + l16) * QKVS_ + h * HD_ + kq * 8;
    qf[g2][0] = *reinterpret_cast<const s16x8*>(qp);
    qf[g2][1] = *reinterpret_cast<const s16x8*>(qp + 32);
  }

  // prologue: stage tile 0 into buf 0; mask for tile 0 into regs
  kstage(0, 0);
  vstage(0, 0);
  int mcur = mask[b * S_ + lane];

  float m_run[2] = {-1e30f, -1e30f}, l_run[2] = {0.f, 0.f};
  f32x4 acc[2][4] = {};                // O^T per group: row d=m*16+kq*4+r, col q=l16
  int cur = 0;

  for (int t = 0; t < NT_; ++t) {
    __syncthreads();                   // buf[cur] ready; buf[cur^1] free
    const bool pfch = (t + 1 < NT_);
    int mnext = 0;
    if (pfch) {
      kstage(cur ^ 1, (t + 1) * 64);   // direct-to-LDS, stays in flight
      vstage(cur ^ 1, (t + 1) * 64);
      mnext = mask[b * S_ + (t + 1) * 64 + lane];
    }

    const u16* ks = &Ks[cur][0];
    const u16* vt = &Vt[cur][0];

    // S^T = K·Q^T (raw scores) for both q-groups; K frag read shared
    f32x4 sc[2][4];
#pragma unroll
    for (int n = 0; n < 4; ++n) {
      f32x4 s0 = {0.f, 0.f, 0.f, 0.f};
      f32x4 s1 = {0.f, 0.f, 0.f, 0.f};
#pragma unroll
      for (int c = 0; c < 2; ++c) {
        const s16x8 kf = *frag64(ks, n * 16 + l16, c * 4 + kq);
        s0 = __builtin_amdgcn_mfma_f32_16x16x32_bf16(kf, qf[0][c], s0, 0, 0, 0);
        s1 = __builtin_amdgcn_mfma_f32_16x16x32_bf16(kf, qf[1][c], s1, 0, 0, 0);
      }
      sc[0][n] = s0;
      sc[1][n] = s1;
    }

    // mask: rare path only (benchmark mask = all-ones -> skipped entirely)
    const unsigned long long mbits = __ballot(mcur != 0);
    if (~mbits) {
#pragma unroll
      for (int n = 0; n < 4; ++n)
#pragma unroll
        for (int r = 0; r < 4; ++r) {
          if (!((mbits >> (n * 16 + kq * 4 + r)) & 1ull)) {
            sc[0][n][r] = -3.0e38f;
            sc[1][n][r] = -3.0e38f;
          }
        }
    }

    union PK { uint32_t u[8]; s16x8 v[2]; } pk[2];
#pragma unroll
    for (int g2 = 0; g2 < 2; ++g2) {
      // raw-domain row max (16 local + 2 shfl across kq)
      float tm = -1e30f;
#pragma unroll
      for (int n = 0; n < 4; ++n)
#pragma unroll
        for (int r = 0; r < 4; ++r) tm = fmaxf(tm, sc[g2][n][r]);
      tm = fmaxf(tm, __shfl_xor(tm, 16));
      tm = fmaxf(tm, __shfl_xor(tm, 32));

      // defer-rescale (T13), raw domain: 44 raw ~= 8 exp2-units
      if (!__all(tm <= m_run[g2] + 44.0f)) {
        const float mnew = fmaxf(m_run[g2], tm);
        const float fac = exp2f((m_run[g2] - mnew) * Cs);
        m_run[g2] = mnew;
        l_run[g2] *= fac;
#pragma unroll
        for (int m = 0; m < 4; ++m)
#pragma unroll
          for (int r = 0; r < 4; ++r) acc[g2][m][r] *= fac;
      }

      // exp2 in scaled domain + sum
      float rs = 0.f;
      const float mneg = -m_run[g2] * Cs;
#pragma unroll
      for (int n = 0; n < 4; ++n)
#pragma unroll
        for (int r = 0; r < 4; ++r) {
          const float p = exp2f(fmaf(sc[g2][n][r], Cs, mneg));
          sc[g2][n][r] = p;
          rs += p;
        }
      rs += __shfl_xor(rs, 16);
      rs += __shfl_xor(rs, 32);
      l_run[g2] += rs;

      // pack P to bf16 pairs -- pk IS the PV B-frag pair (zero-shuffle)
#pragma unroll
      for (int n = 0; n < 4; ++n) {
        asm("v_cvt_pk_bf16_f32 %0, %1, %2"
            : "=v"(pk[g2].u[2 * n]) : "v"(sc[g2][n][0]), "v"(sc[g2][n][1]));
        asm("v_cvt_pk_bf16_f32 %0, %1, %2"
            : "=v"(pk[g2].u[2 * n + 1]) : "v"(sc[g2][n][2]), "v"(sc[g2][n][3]));
      }
    }

    // O^T += V^T·P^T under pi: V A-frag = two b64 chunks per (m,c)
    const int hs = kq >> 1;            // high slot bit from kq
    const int bo = 4 * (kq & 1);       // within-slot element offset
#pragma unroll
    for (int m = 0; m < 4; ++m) {
      const int drow = m * 16 + l16;
      const u16* vr = vt + drow * 64;
      union VF { s16x4 h[2]; s16x8 v; } vf0, vf1;
      vf0.h[0] = *reinterpret_cast<const s16x4*>(vr + swz64(drow, hs) * 8 + bo);
      vf0.h[1] = *reinterpret_cast<const s16x4*>(vr + swz64(drow, 2 + hs) * 8 + bo);
      vf1.h[0] = *reinterpret_cast<const s16x4*>(vr + swz64(drow, 4 + hs) * 8 + bo);
      vf1.h[1] = *reinterpret_cast<const s16x4*>(vr + swz64(drow, 6 + hs) * 8 + bo);
      acc[0][m] = __builtin_amdgcn_mfma_f32_16x16x32_bf16(vf0.v, pk[0].v[0], acc[0][m], 0, 0, 0);
      acc[0][m] = __builtin_amdgcn_mfma_f32_16x16x32_bf16(vf1.v, pk[0].v[1], acc[0][m], 0, 0, 0);
      acc[1][m] = __builtin_amdgcn_mfma_f32_16x16x32_bf16(vf0.v, pk[1].v[0], acc[1][m], 0, 0, 0);
      acc[1][m] = __builtin_amdgcn_mfma_f32_16x16x32_bf16(vf1.v, pk[1].v[1], acc[1][m], 0, 0, 0);
    }

    mcur = mnext;
    cur ^= 1;
  }

  // normalize + store O^T -> O (bf16, token-major [BS][D])
#pragma unroll
  for (int g2 = 0; g2 < 2; ++g2) {
    const float rl = 1.0f / l_run[g2];
    u16* op = O + (size_t)(b * S_ + q0 + g2 * 16 + l16) * D_ + h * HD_ + kq * 4;
#pragma unroll
    for (int m = 0; m < 4; ++m) {
      uint2 o;
      o.x = (uint32_t)f2b(acc[g2][m][0] * rl) | ((uint32_t)f2b(acc[g2][m][1] * rl) << 16);
      o.y = (uint32_t)f2b(acc[g2][m][2] * rl) | ((uint32_t)f2b(acc[g2][m][3] * rl) << 16);
      *reinterpret_cast<uint2*>(op + m * 16) = o;
    }
  }
}

// ---------------- launch ----------------
extern "C" void kernel_launch(void* const* d_in, const int* in_sizes, int n_in,
                              void* d_out, int out_size, void* d_ws, size_t ws_size,
                              hipStream_t stream) {
  const float* x = (const float*)d_in[0];
  const int* mask = (const int*)d_in[1];
  const float* Wq = (const float*)d_in[2];
  const float* Wk = (const float*)d_in[3];
  const float* Wv = (const float*)d_in[4];
  const float* Wo = (const float*)d_in[5];

  char* w = (char*)d_ws;
  u16* xb = (u16*)w;    w += (size_t)BS_ * D_ * 2;     // contiguous cvt dst
  u16* Wqkvb = (u16*)w; w += (size_t)QKVS_ * D_ * 2;
  u16* Wob = (u16*)w;   w += (size_t)D_ * D_ * 2;
  u16* QKVw = (u16*)w;  w += (size_t)BS_ * QKVS_ * 2;
  u16* VTw = (u16*)w;   w += (size_t)B_ * KVH_ * HD_ * S_ * 2;
  u16* AOw = (u16*)w;   w += (size_t)BS_ * D_ * 2;

  const int n4tot = (BS_ * D_ + QKVS_ * D_ + D_ * D_) / 4;
  cvt5_kernel<<<dim3(2048), dim3(256), 0, stream>>>(x, Wq, Wk, Wv, Wo, xb, n4tot);

  // fused QKV projection: (4096 x 1536), 64x128 tiles -> 768 blocks (3/CU)
  gemm64<1><<<dim3(QKVS_ / 128, BS_ / 64), dim3(256), 0, stream>>>(xb, Wqkvb, QKVw, BS_, QKVS_, D_);
  // transpose V for direct LDS staging
  vtrans_kernel<<<dim3(S_ / 64, B_ * KVH_), dim3(256), 0, stream>>>(QKVw, VTw);
  // attention: (S/32, B*KVH) blocks of 4 waves, 32 q-rows/wave
  attn_kernel<<<dim3(S_ / 32, B_ * KVH_), dim3(256), 0, stream>>>(QKVw, VTw, mask, AOw);
  // output projection -> fp32 d_out, 64x128 tiles -> 512 blocks (2/CU)
  gemm64<0><<<dim3(D_ / 128, BS_ / 64), dim3(256), 0, stream>>>(AOw, Wob, (float*)d_out, BS_, D_, D_);
}

// Round 15
// 134.226 us; speedup vs baseline: 1.1948x; 1.0402x over previous
//
#include <hip/hip_runtime.h>
#include <hip/hip_bf16.h>
#include <stdint.h>

// Problem constants (GroupedQueryAttention: B=2,S=2048,D=1024,H=16,KVH=4)
#define B_    2
#define S_    2048
#define D_    1024
#define H_    16
#define KVH_  4
#define HD_   64
#define REP_  4
#define BS_   (B_ * S_)        // 4096 tokens
#define KVD_  256
#define QKVS_ 1536             // fused QKV row stride: Q(1024) | K(256) | V(256)
#define NT_   (S_ / 64)        // 32 KV tiles

typedef unsigned short u16;
typedef short s16x4 __attribute__((ext_vector_type(4)));
typedef short s16x8 __attribute__((ext_vector_type(8)));
typedef float f32x4 __attribute__((ext_vector_type(4)));

typedef const __attribute__((address_space(1))) void* gvp;
typedef __attribute__((address_space(3))) void* lvp;

#define MFMA16(a, b, c) __builtin_amdgcn_mfma_f32_16x16x32_bf16((a), (b), (c), 0, 0, 0)

__device__ __forceinline__ u16 f2b(float f) {  // RNE f32->bf16 (finite inputs)
  uint32_t u = __float_as_uint(f);
  u += 0x7fffu + ((u >> 16) & 1u);
  return (u16)(u >> 16);
}

// XOR swizzle for 64-elem-wide bf16 LDS rows (128B = 8 x 16B slots).
__device__ __forceinline__ int swz64(int row, int slot) {
  return slot ^ (row & 7) ^ ((row >> 3) & 7);
}

// ---------------- fused f32 -> bf16 conversion over 5 segments ----------------
#define N0_ (BS_ * D_ / 4)
#define N1_ (D_ * D_ / 4)
#define N2_ (KVD_ * D_ / 4)
__global__ void cvt5_kernel(const float* __restrict__ s0, const float* __restrict__ s1,
                            const float* __restrict__ s2, const float* __restrict__ s3,
                            const float* __restrict__ s4, u16* __restrict__ dst, int n4tot) {
  for (int i = blockIdx.x * blockDim.x + threadIdx.x; i < n4tot;
       i += gridDim.x * blockDim.x) {
    const float* src;
    int j = i;
    if (j < N0_) src = s0;
    else if ((j -= N0_) < N1_) src = s1;
    else if ((j -= N1_) < N2_) src = s2;
    else if ((j -= N2_) < N2_) src = s3;
    else { j -= N2_; src = s4; }
    const float4 v = reinterpret_cast<const float4*>(src)[j];
    uint2 o;
    o.x = (uint32_t)f2b(v.x) | ((uint32_t)f2b(v.y) << 16);
    o.y = (uint32_t)f2b(v.z) | ((uint32_t)f2b(v.w) << 16);
    reinterpret_cast<uint2*>(dst)[i] = o;
  }
}

// ---------------- bf16 GEMM, C = A(MxK) * B(NxK)^T, 64x128 tile ----------------
template <int OUT_BF16>
__global__ __launch_bounds__(256) void gemm64(const u16* __restrict__ A,
                                              const u16* __restrict__ Bw,
                                              void* __restrict__ Cout,
                                              int M, int N, int K) {
  __shared__ u16 As[64 * 32];
  __shared__ u16 Bs[128 * 32];
  const int tid = threadIdx.x;
  const int lane = tid & 63;
  const int wid = tid >> 6;
  const int l16 = lane & 15;
  const int kq = lane >> 4;
  const int bm = blockIdx.y * 64;
  const int bn = blockIdx.x * 128;
  const int wr = (wid >> 1) * 32;
  const int wc = (wid & 1) * 64;

  f32x4 acc[2][4] = {};

  for (int kt = 0; kt < K; kt += 32) {
    __syncthreads();
    {  // A tile: 64x32, 1 load/thread
      const int e = tid * 8;
      const int row = e >> 5;
      const int col = e & 31;
      __builtin_amdgcn_global_load_lds((gvp)(A + (size_t)(bm + row) * K + kt + col),
                                       (lvp)(&As[e]), 16, 0, 0);
    }
#pragma unroll
    for (int i = 0; i < 2; ++i) {  // B tile: 128x32, 2 loads/thread
      const int e = (i * 256 + tid) * 8;
      const int row = e >> 5;
      const int col = e & 31;
      __builtin_amdgcn_global_load_lds((gvp)(Bw + (size_t)(bn + row) * K + kt + col),
                                       (lvp)(&Bs[e]), 16, 0, 0);
    }
    __syncthreads();

    s16x8 af[2], bfr[4];
#pragma unroll
    for (int m = 0; m < 2; ++m)
      af[m] = *reinterpret_cast<const s16x8*>(&As[(wr + m * 16 + l16) * 32 + kq * 8]);
#pragma unroll
    for (int n = 0; n < 4; ++n)
      bfr[n] = *reinterpret_cast<const s16x8*>(&Bs[(wc + n * 16 + l16) * 32 + kq * 8]);
#pragma unroll
    for (int m = 0; m < 2; ++m)
#pragma unroll
      for (int n = 0; n < 4; ++n)
        acc[m][n] = MFMA16(af[m], bfr[n], acc[m][n]);
  }

#pragma unroll
  for (int m = 0; m < 2; ++m) {
    const int row0 = bm + wr + m * 16 + kq * 4;
#pragma unroll
    for (int n = 0; n < 4; ++n) {
      const int col = bn + wc + n * 16 + l16;
#pragma unroll
      for (int r = 0; r < 4; ++r) {
        if (OUT_BF16) {
          ((u16*)Cout)[(size_t)(row0 + r) * N + col] = f2b(acc[m][n][r]);
        } else {
          ((float*)Cout)[(size_t)(row0 + r) * N + col] = acc[m][n][r];
        }
      }
    }
  }
}

// ---------------- V transpose: QKV V-part -> VT[(b*4+g)*64 + d][s] ----------------
__global__ __launch_bounds__(256) void vtrans_kernel(const u16* __restrict__ QKV,
                                                     u16* __restrict__ VT) {
  __shared__ u16 T[64][72];
  const int tid = threadIdx.x;
  const int s0 = blockIdx.x * 64;
  const int bg = blockIdx.y;
  const int b = bg >> 2;
  const int g = bg & 3;
  const int r = tid >> 2;
  const int c0 = (tid & 3) * 16;
  const u16* src = QKV + (size_t)(b * S_ + s0 + r) * QKVS_ + D_ + KVD_ + g * HD_ + c0;
  const uint4 a = reinterpret_cast<const uint4*>(src)[0];
  const uint4 bq = reinterpret_cast<const uint4*>(src)[1];
  *reinterpret_cast<uint4*>(&T[r][c0]) = a;
  *reinterpret_cast<uint4*>(&T[r][c0 + 8]) = bq;
  __syncthreads();
  const int d = tid >> 2;
  u16 tmp[16];
#pragma unroll
  for (int j = 0; j < 16; ++j) tmp[j] = T[c0 + j][d];
  u16* dst = VT + ((size_t)bg * 64 + d) * S_ + s0 + c0;
  *reinterpret_cast<uint4*>(dst) = *reinterpret_cast<const uint4*>(&tmp[0]);
  *reinterpret_cast<uint4*>(dst + 8) = *reinterpret_cast<const uint4*>(&tmp[8]);
}

// ---------------- flash attention (GQA): zero-shuffle PV, hoisted addressing ----------------
// All LDS frag offsets precomputed per-thread; tile loop unrolled x2 so the
// double-buffer base is compile-time in each phase; K/V frags preloaded to
// regs then MFMA bursts wrapped in s_setprio (T5).
__global__ __launch_bounds__(256) void attn_kernel(const u16* __restrict__ QKV,
                                                   const u16* __restrict__ VT,
                                                   const int* __restrict__ mask,
                                                   u16* __restrict__ O) {
  __shared__ u16 Ks[2][64 * 64];
  __shared__ u16 Vt[2][64 * 64];       // Vt[d][kv], slot-swizzled

  const int tid = threadIdx.x;
  const int lane = tid & 63;
  const int wid = tid >> 6;            // 0..3 = head within group
  const int l16 = lane & 15;
  const int kq = lane >> 4;            // 0..3
  const int bg = blockIdx.y;
  const int b = bg >> 2;               // / KVH
  const int g = bg & 3;
  const int h = g * REP_ + wid;
  const int q0 = blockIdx.x * 32;
  const u16* kv_base = QKV + (size_t)b * S_ * QKVS_ + D_ + g * HD_;  // K cols
  const u16* vt_base = VT + (size_t)bg * 64 * S_;                     // V^T rows
  const int* maskp = mask + b * S_ + lane;
  const float Cs = 0.18033688011112042f;  // SCALE * log2(e)

  // ---- precomputed per-thread LDS element offsets (loop-invariant) ----
  int koff[4][2];
#pragma unroll
  for (int n = 0; n < 4; ++n)
#pragma unroll
    for (int c = 0; c < 2; ++c) {
      const int row = n * 16 + l16;
      koff[n][c] = row * 64 + swz64(row, c * 4 + kq) * 8;
    }
  const int hs = kq >> 1;
  const int bo = 4 * (kq & 1);
  int voff[4][4];
#pragma unroll
  for (int m = 0; m < 4; ++m) {
    const int drow = m * 16 + l16;
    voff[m][0] = drow * 64 + swz64(drow, hs) * 8 + bo;
    voff[m][1] = drow * 64 + swz64(drow, 2 + hs) * 8 + bo;
    voff[m][2] = drow * 64 + swz64(drow, 4 + hs) * 8 + bo;
    voff[m][3] = drow * 64 + swz64(drow, 6 + hs) * 8 + bo;
  }
  int kst_src[2], vst_src[2], st_dst[2];
#pragma unroll
  for (int i = 0; i < 2; ++i) {
    const int e = (i * 256 + tid) * 8;
    const int row = e >> 6;
    const int slot = (e >> 3) & 7;
    st_dst[i] = e;
    kst_src[i] = row * QKVS_ + swz64(row, slot) * 8;  // + kv0*QKVS_
    vst_src[i] = row * S_ + swz64(row, slot) * 8;     // + kv0
  }

  auto kstage = [&](int buf, int kv0) {
#pragma unroll
    for (int i = 0; i < 2; ++i)
      __builtin_amdgcn_global_load_lds(
          (gvp)(kv_base + (size_t)kv0 * QKVS_ + kst_src[i]),
          (lvp)(&Ks[buf][st_dst[i]]), 16, 0, 0);
  };
  auto vstage = [&](int buf, int kv0) {
#pragma unroll
    for (int i = 0; i < 2; ++i)
      __builtin_amdgcn_global_load_lds(
          (gvp)(vt_base + kv0 + vst_src[i]),
          (lvp)(&Vt[buf][st_dst[i]]), 16, 0, 0);
  };

  // Q B-frags: qf[g2][c] = Q[q0+g2*16+l16][c*32+kq*8..]
  s16x8 qf[2][2];
#pragma unroll
  for (int g2 = 0; g2 < 2; ++g2) {
    const u16* qp = QKV + (size_t)(b * S_ + q0 + g2 * 16 + l16) * QKVS_ + h * HD_ + kq * 8;
    qf[g2][0] = *reinterpret_cast<const s16x8*>(qp);
    qf[g2][1] = *reinterpret_cast<const s16x8*>(qp + 32);
  }

  // prologue: stage tile 0 into buf 0; mask tile 0 into regs
  kstage(0, 0);
  vstage(0, 0);
  int mcur = maskp[0];

  float m_run[2] = {-1e30f, -1e30f}, l_run[2] = {0.f, 0.f};
  f32x4 acc[2][4] = {};                // O^T per group: row d=m*16+kq*4+r, col q=l16

#define ATTN_TILE(T_, BUF_)                                                       \
  {                                                                               \
    const int t_ = (T_);                                                          \
    __syncthreads();                                                              \
    const bool pfch = (t_ + 1 < NT_);                                             \
    int mnext = 0;                                                                \
    if (pfch) {                                                                   \
      kstage((BUF_) ^ 1, (t_ + 1) * 64);                                          \
      vstage((BUF_) ^ 1, (t_ + 1) * 64);                                          \
      mnext = maskp[(t_ + 1) * 64];                                               \
    }                                                                             \
    const u16* ks = &Ks[(BUF_)][0];                                               \
    const u16* vt = &Vt[(BUF_)][0];                                               \
    s16x8 kfr[4][2];                                                              \
    _Pragma("unroll") for (int n = 0; n < 4; ++n) {                               \
      kfr[n][0] = *reinterpret_cast<const s16x8*>(ks + koff[n][0]);               \
      kfr[n][1] = *reinterpret_cast<const s16x8*>(ks + koff[n][1]);               \
    }                                                                             \
    f32x4 sc[2][4];                                                               \
    __builtin_amdgcn_s_setprio(1);                                                \
    _Pragma("unroll") for (int n = 0; n < 4; ++n) {                               \
      f32x4 s0 = {0.f, 0.f, 0.f, 0.f};                                            \
      f32x4 s1 = {0.f, 0.f, 0.f, 0.f};                                            \
      s0 = MFMA16(kfr[n][0], qf[0][0], s0);                                       \
      s1 = MFMA16(kfr[n][0], qf[1][0], s1);                                       \
      s0 = MFMA16(kfr[n][1], qf[0][1], s0);                                       \
      s1 = MFMA16(kfr[n][1], qf[1][1], s1);                                       \
      sc[0][n] = s0;                                                              \
      sc[1][n] = s1;                                                              \
    }                                                                             \
    __builtin_amdgcn_s_setprio(0);                                                \
    const unsigned long long mbits = __ballot(mcur != 0);                         \
    if (~mbits) {                                                                 \
      _Pragma("unroll") for (int n = 0; n < 4; ++n)                               \
      _Pragma("unroll") for (int r = 0; r < 4; ++r) {                             \
        if (!((mbits >> (n * 16 + kq * 4 + r)) & 1ull)) {                         \
          sc[0][n][r] = -3.0e38f;                                                 \
          sc[1][n][r] = -3.0e38f;                                                 \
        }                                                                         \
      }                                                                           \
    }                                                                             \
    union PK { uint32_t u[8]; s16x8 v[2]; } pk[2];                                \
    _Pragma("unroll") for (int g2 = 0; g2 < 2; ++g2) {                            \
      float tm = -1e30f;                                                          \
      _Pragma("unroll") for (int n = 0; n < 4; ++n)                               \
      _Pragma("unroll") for (int r = 0; r < 4; ++r)                               \
          tm = fmaxf(tm, sc[g2][n][r]);                                           \
      tm = fmaxf(tm, __shfl_xor(tm, 16));                                         \
      tm = fmaxf(tm, __shfl_xor(tm, 32));                                         \
      if (!__all(tm <= m_run[g2] + 44.0f)) {                                      \
        const float mnew = fmaxf(m_run[g2], tm);                                  \
        const float fac = exp2f((m_run[g2] - mnew) * Cs);                         \
        m_run[g2] = mnew;                                                         \
        l_run[g2] *= fac;                                                         \
        _Pragma("unroll") for (int m = 0; m < 4; ++m)                             \
        _Pragma("unroll") for (int r = 0; r < 4; ++r) acc[g2][m][r] *= fac;       \
      }                                                                           \
      float rs = 0.f;                                                             \
      const float mneg = -m_run[g2] * Cs;                                         \
      _Pragma("unroll") for (int n = 0; n < 4; ++n)                               \
      _Pragma("unroll") for (int r = 0; r < 4; ++r) {                             \
        const float p = exp2f(fmaf(sc[g2][n][r], Cs, mneg));                      \
        sc[g2][n][r] = p;                                                         \
        rs += p;                                                                  \
      }                                                                           \
      rs += __shfl_xor(rs, 16);                                                   \
      rs += __shfl_xor(rs, 32);                                                   \
      l_run[g2] += rs;                                                            \
      _Pragma("unroll") for (int n = 0; n < 4; ++n) {                             \
        asm("v_cvt_pk_bf16_f32 %0, %1, %2"                                        \
            : "=v"(pk[g2].u[2 * n]) : "v"(sc[g2][n][0]), "v"(sc[g2][n][1]));      \
        asm("v_cvt_pk_bf16_f32 %0, %1, %2"                                        \
            : "=v"(pk[g2].u[2 * n + 1]) : "v"(sc[g2][n][2]), "v"(sc[g2][n][3]));  \
      }                                                                           \
    }                                                                             \
    s16x8 vfr[4][2];                                                              \
    _Pragma("unroll") for (int m = 0; m < 4; ++m) {                               \
      union VF { s16x4 h[2]; s16x8 v; } va, vb;                                   \
      va.h[0] = *reinterpret_cast<const s16x4*>(vt + voff[m][0]);                 \
      va.h[1] = *reinterpret_cast<const s16x4*>(vt + voff[m][1]);                 \
      vb.h[0] = *reinterpret_cast<const s16x4*>(vt + voff[m][2]);                 \
      vb.h[1] = *reinterpret_cast<const s16x4*>(vt + voff[m][3]);                 \
      vfr[m][0] = va.v;                                                           \
      vfr[m][1] = vb.v;                                                           \
    }                                                                             \
    __builtin_amdgcn_s_setprio(1);                                                \
    _Pragma("unroll") for (int m = 0; m < 4; ++m) {                               \
      acc[0][m] = MFMA16(vfr[m][0], pk[0].v[0], acc[0][m]);                       \
      acc[1][m] = MFMA16(vfr[m][0], pk[1].v[0], acc[1][m]);                       \
      acc[0][m] = MFMA16(vfr[m][1], pk[0].v[1], acc[0][m]);                       \
      acc[1][m] = MFMA16(vfr[m][1], pk[1].v[1], acc[1][m]);                       \
    }                                                                             \
    __builtin_amdgcn_s_setprio(0);                                                \
    mcur = mnext;                                                                 \
  }

  for (int t = 0; t < NT_; t += 2) {
    ATTN_TILE(t, 0)
    ATTN_TILE(t + 1, 1)
  }
#undef ATTN_TILE

  // normalize + store O^T -> O (bf16, token-major [BS][D])
#pragma unroll
  for (int g2 = 0; g2 < 2; ++g2) {
    const float rl = 1.0f / l_run[g2];
    u16* op = O + (size_t)(b * S_ + q0 + g2 * 16 + l16) * D_ + h * HD_ + kq * 4;
#pragma unroll
    for (int m = 0; m < 4; ++m) {
      uint2 o;
      o.x = (uint32_t)f2b(acc[g2][m][0] * rl) | ((uint32_t)f2b(acc[g2][m][1] * rl) << 16);
      o.y = (uint32_t)f2b(acc[g2][m][2] * rl) | ((uint32_t)f2b(acc[g2][m][3] * rl) << 16);
      *reinterpret_cast<uint2*>(op + m * 16) = o;
    }
  }
}

// ---------------- launch ----------------
extern "C" void kernel_launch(void* const* d_in, const int* in_sizes, int n_in,
                              void* d_out, int out_size, void* d_ws, size_t ws_size,
                              hipStream_t stream) {
  const float* x = (const float*)d_in[0];
  const int* mask = (const int*)d_in[1];
  const float* Wq = (const float*)d_in[2];
  const float* Wk = (const float*)d_in[3];
  const float* Wv = (const float*)d_in[4];
  const float* Wo = (const float*)d_in[5];

  char* w = (char*)d_ws;
  u16* xb = (u16*)w;    w += (size_t)BS_ * D_ * 2;     // contiguous cvt dst
  u16* Wqkvb = (u16*)w; w += (size_t)QKVS_ * D_ * 2;
  u16* Wob = (u16*)w;   w += (size_t)D_ * D_ * 2;
  u16* QKVw = (u16*)w;  w += (size_t)BS_ * QKVS_ * 2;
  u16* VTw = (u16*)w;   w += (size_t)B_ * KVH_ * HD_ * S_ * 2;
  u16* AOw = (u16*)w;   w += (size_t)BS_ * D_ * 2;

  const int n4tot = (BS_ * D_ + QKVS_ * D_ + D_ * D_) / 4;
  cvt5_kernel<<<dim3(2048), dim3(256), 0, stream>>>(x, Wq, Wk, Wv, Wo, xb, n4tot);

  // fused QKV projection: (4096 x 1536), 64x128 tiles -> 768 blocks (3/CU)
  gemm64<1><<<dim3(QKVS_ / 128, BS_ / 64), dim3(256), 0, stream>>>(xb, Wqkvb, QKVw, BS_, QKVS_, D_);
  // transpose V for direct LDS staging
  vtrans_kernel<<<dim3(S_ / 64, B_ * KVH_), dim3(256), 0, stream>>>(QKVw, VTw);
  // attention: (S/32, B*KVH) blocks of 4 waves, 32 q-rows/wave
  attn_kernel<<<dim3(S_ / 32, B_ * KVH_), dim3(256), 0, stream>>>(QKVw, VTw, mask, AOw);
  // output projection -> fp32 d_out, 64x128 tiles -> 512 blocks (2/CU)
  gemm64<0><<<dim3(D_ / 128, BS_ / 64), dim3(256), 0, stream>>>(AOw, Wob, (float*)d_out, BS_, D_, D_);
}

// Round 17
// 127.634 us; speedup vs baseline: 1.2565x; 1.0516x over previous
//
#include <hip/hip_runtime.h>
#include <hip/hip_bf16.h>
#include <stdint.h>

// Problem constants (GroupedQueryAttention: B=2,S=2048,D=1024,H=16,KVH=4)
#define B_    2
#define S_    2048
#define D_    1024
#define H_    16
#define KVH_  4
#define HD_   64
#define REP_  4
#define BS_   (B_ * S_)        // 4096 tokens
#define KVD_  256
#define QKVS_ 1536             // fused QKV row stride: Q(1024) | K(256) | V(256)
#define NTT_  (S_ / 128)       // 16 KV tiles of 128

typedef unsigned short u16;
typedef short s16x4 __attribute__((ext_vector_type(4)));
typedef short s16x8 __attribute__((ext_vector_type(8)));
typedef float f32x4 __attribute__((ext_vector_type(4)));

typedef const __attribute__((address_space(1))) void* gvp;
typedef __attribute__((address_space(3))) void* lvp;

#define MFMA16(a, b, c) __builtin_amdgcn_mfma_f32_16x16x32_bf16((a), (b), (c), 0, 0, 0)

__device__ __forceinline__ u16 f2b(float f) {  // RNE f32->bf16 (finite inputs)
  uint32_t u = __float_as_uint(f);
  u += 0x7fffu + ((u >> 16) & 1u);
  return (u16)(u >> 16);
}

// XOR swizzles: 64-wide rows (8 x 16B slots) and 128-wide rows (16 slots).
__device__ __forceinline__ int swz64(int row, int slot) {
  return slot ^ (row & 7) ^ ((row >> 3) & 7);
}
__device__ __forceinline__ int swz128(int row, int slot) {
  return slot ^ (row & 15);
}

// ---------------- fused f32 -> bf16 conversion over 5 segments ----------------
#define N0_ (BS_ * D_ / 4)
#define N1_ (D_ * D_ / 4)
#define N2_ (KVD_ * D_ / 4)
__global__ void cvt5_kernel(const float* __restrict__ s0, const float* __restrict__ s1,
                            const float* __restrict__ s2, const float* __restrict__ s3,
                            const float* __restrict__ s4, u16* __restrict__ dst, int n4tot) {
  for (int i = blockIdx.x * blockDim.x + threadIdx.x; i < n4tot;
       i += gridDim.x * blockDim.x) {
    const float* src;
    int j = i;
    if (j < N0_) src = s0;
    else if ((j -= N0_) < N1_) src = s1;
    else if ((j -= N1_) < N2_) src = s2;
    else if ((j -= N2_) < N2_) src = s3;
    else { j -= N2_; src = s4; }
    const float4 v = reinterpret_cast<const float4*>(src)[j];
    uint2 o;
    o.x = (uint32_t)f2b(v.x) | ((uint32_t)f2b(v.y) << 16);
    o.y = (uint32_t)f2b(v.z) | ((uint32_t)f2b(v.w) << 16);
    reinterpret_cast<uint2*>(dst)[i] = o;
  }
}

// ---------------- bf16 GEMM, C = A(MxK) * B(NxK)^T, 64x128 tile ----------------
// XCD-aware bijective block swizzle (nwg % 8 == 0 for both launches here).
template <int OUT_BF16>
__global__ __launch_bounds__(256) void gemm64(const u16* __restrict__ A,
                                              const u16* __restrict__ Bw,
                                              void* __restrict__ Cout,
                                              int M, int N, int K) {
  __shared__ u16 As[64 * 32];
  __shared__ u16 Bs[128 * 32];
  const int tid = threadIdx.x;
  const int lane = tid & 63;
  const int wid = tid >> 6;
  const int l16 = lane & 15;
  const int kq = lane >> 4;
  // XCD swizzle: hw-blocks on one XCD (bid0 mod 8) get a contiguous logical chunk
  const int nwg = gridDim.x * gridDim.y;
  const int bid0 = blockIdx.y * gridDim.x + blockIdx.x;
  const int bid = (bid0 & 7) * (nwg >> 3) + (bid0 >> 3);
  const int bm = (bid / gridDim.x) * 64;
  const int bn = (bid % gridDim.x) * 128;
  const int wr = (wid >> 1) * 32;
  const int wc = (wid & 1) * 64;

  f32x4 acc[2][4] = {};

  for (int kt = 0; kt < K; kt += 32) {
    __syncthreads();
    {  // A tile: 64x32, 1 load/thread
      const int e = tid * 8;
      const int row = e >> 5;
      const int col = e & 31;
      __builtin_amdgcn_global_load_lds((gvp)(A + (size_t)(bm + row) * K + kt + col),
                                       (lvp)(&As[e]), 16, 0, 0);
    }
#pragma unroll
    for (int i = 0; i < 2; ++i) {  // B tile: 128x32, 2 loads/thread
      const int e = (i * 256 + tid) * 8;
      const int row = e >> 5;
      const int col = e & 31;
      __builtin_amdgcn_global_load_lds((gvp)(Bw + (size_t)(bn + row) * K + kt + col),
                                       (lvp)(&Bs[e]), 16, 0, 0);
    }
    __syncthreads();

    s16x8 af[2], bfr[4];
#pragma unroll
    for (int m = 0; m < 2; ++m)
      af[m] = *reinterpret_cast<const s16x8*>(&As[(wr + m * 16 + l16) * 32 + kq * 8]);
#pragma unroll
    for (int n = 0; n < 4; ++n)
      bfr[n] = *reinterpret_cast<const s16x8*>(&Bs[(wc + n * 16 + l16) * 32 + kq * 8]);
#pragma unroll
    for (int m = 0; m < 2; ++m)
#pragma unroll
      for (int n = 0; n < 4; ++n)
        acc[m][n] = MFMA16(af[m], bfr[n], acc[m][n]);
  }

#pragma unroll
  for (int m = 0; m < 2; ++m) {
    const int row0 = bm + wr + m * 16 + kq * 4;
#pragma unroll
    for (int n = 0; n < 4; ++n) {
      const int col = bn + wc + n * 16 + l16;
#pragma unroll
      for (int r = 0; r < 4; ++r) {
        if (OUT_BF16) {
          ((u16*)Cout)[(size_t)(row0 + r) * N + col] = f2b(acc[m][n][r]);
        } else {
          ((float*)Cout)[(size_t)(row0 + r) * N + col] = acc[m][n][r];
        }
      }
    }
  }
}

// ---------------- V transpose: QKV V-part -> VT[(b*4+g)*64 + d][s] ----------------
__global__ __launch_bounds__(256) void vtrans_kernel(const u16* __restrict__ QKV,
                                                     u16* __restrict__ VT) {
  __shared__ u16 T[64][72];
  const int tid = threadIdx.x;
  const int s0 = blockIdx.x * 64;
  const int bg = blockIdx.y;
  const int b = bg >> 2;
  const int g = bg & 3;
  const int r = tid >> 2;
  const int c0 = (tid & 3) * 16;
  const u16* src = QKV + (size_t)(b * S_ + s0 + r) * QKVS_ + D_ + KVD_ + g * HD_ + c0;
  const uint4 a = reinterpret_cast<const uint4*>(src)[0];
  const uint4 bq = reinterpret_cast<const uint4*>(src)[1];
  *reinterpret_cast<uint4*>(&T[r][c0]) = a;
  *reinterpret_cast<uint4*>(&T[r][c0 + 8]) = bq;
  __syncthreads();
  const int d = tid >> 2;
  u16 tmp[16];
#pragma unroll
  for (int j = 0; j < 16; ++j) tmp[j] = T[c0 + j][d];
  u16* dst = VT + ((size_t)bg * 64 + d) * S_ + s0 + c0;
  *reinterpret_cast<uint4*>(dst) = *reinterpret_cast<const uint4*>(&tmp[0]);
  *reinterpret_cast<uint4*>(dst + 8) = *reinterpret_cast<const uint4*>(&tmp[8]);
}

// ---------------- flash attention (GQA): zero-shuffle PV, KVBLK=128 ----------------
// Per-tile fixed costs (barriers, shfl-reductions, rescale checks, staging
// issue) amortized over 128 kv instead of 64. All frag offsets precomputed;
// dbuf unrolled x2; MFMA bursts in s_setprio (T5).
__global__ __launch_bounds__(256, 2) void attn_kernel(const u16* __restrict__ QKV,
                                                      const u16* __restrict__ VT,
                                                      const int* __restrict__ mask,
                                                      u16* __restrict__ O) {
  __shared__ u16 Ks[2][128 * 64];      // K rows, 64-wide swizzled
  __shared__ u16 Vt[2][64 * 128];      // V^T rows (d), 128-wide swizzled

  const int tid = threadIdx.x;
  const int lane = tid & 63;
  const int wid = tid >> 6;            // 0..3 = head within group
  const int l16 = lane & 15;
  const int kq = lane >> 4;            // 0..3
  const int bg = blockIdx.y;
  const int b = bg >> 2;               // / KVH
  const int g = bg & 3;
  const int h = g * REP_ + wid;
  const int q0 = blockIdx.x * 32;
  const u16* kv_base = QKV + (size_t)b * S_ * QKVS_ + D_ + g * HD_;  // K cols
  const u16* vt_base = VT + (size_t)bg * 64 * S_;                     // V^T rows
  const int* maskp = mask + b * S_ + lane;
  const float Cs = 0.18033688011112042f;  // SCALE * log2(e)

  // ---- precomputed per-thread LDS element offsets (loop-invariant) ----
  int koff[8][2];
#pragma unroll
  for (int n = 0; n < 8; ++n)
#pragma unroll
    for (int c = 0; c < 2; ++c) {
      const int row = n * 16 + l16;
      koff[n][c] = row * 64 + swz64(row, c * 4 + kq) * 8;
    }
  const int hs = kq >> 1;
  const int bo = 4 * (kq & 1);
  int vbase[8];                        // voff = vbase[j] + m*2048  (drow&15 == l16)
#pragma unroll
  for (int c = 0; c < 4; ++c) {
    vbase[2 * c] = l16 * 128 + swz128(l16, 4 * c + hs) * 8 + bo;
    vbase[2 * c + 1] = l16 * 128 + swz128(l16, 4 * c + 2 + hs) * 8 + bo;
  }
  int kst_src[4], vst_src[4], st_dst[4];
#pragma unroll
  for (int i = 0; i < 4; ++i) {
    const int e = (i * 256 + tid) * 8;
    st_dst[i] = e;
    const int krow = e >> 6;
    kst_src[i] = krow * QKVS_ + swz64(krow, (e >> 3) & 7) * 8;   // + kv0*QKVS_
    const int vrow = e >> 7;
    vst_src[i] = vrow * S_ + swz128(vrow, (e >> 3) & 15) * 8;    // + kv0
  }

  auto kstage = [&](int buf, int kv0) {
#pragma unroll
    for (int i = 0; i < 4; ++i)
      __builtin_amdgcn_global_load_lds(
          (gvp)(kv_base + (size_t)kv0 * QKVS_ + kst_src[i]),
          (lvp)(&Ks[buf][st_dst[i]]), 16, 0, 0);
  };
  auto vstage = [&](int buf, int kv0) {
#pragma unroll
    for (int i = 0; i < 4; ++i)
      __builtin_amdgcn_global_load_lds(
          (gvp)(vt_base + kv0 + vst_src[i]),
          (lvp)(&Vt[buf][st_dst[i]]), 16, 0, 0);
  };

  // Q B-frags: qf[g2][c] = Q[q0+g2*16+l16][c*32+kq*8..]
  s16x8 qf[2][2];
#pragma unroll
  for (int g2 = 0; g2 < 2; ++g2) {
    const u16* qp = QKV + (size_t)(b * S_ + q0 + g2 * 16 + l16) * QKVS_ + h * HD_ + kq * 8;
    qf[g2][0] = *reinterpret_cast<const s16x8*>(qp);
    qf[g2][1] = *reinterpret_cast<const s16x8*>(qp + 32);
  }

  // prologue: stage tile 0 into buf 0; mask tile 0 into regs
  kstage(0, 0);
  vstage(0, 0);
  int mcur0 = maskp[0];
  int mcur1 = maskp[64];

  float m_run[2] = {-1e30f, -1e30f}, l_run[2] = {0.f, 0.f};
  f32x4 acc[2][4] = {};                // O^T per group: row d=m*16+kq*4+r, col q=l16

#define ATTN_TILE(T_, BUF_)                                                       \
  {                                                                               \
    const int t_ = (T_);                                                          \
    __syncthreads();                                                              \
    const bool pfch = (t_ + 1 < NTT_);                                            \
    int mnext0 = 0, mnext1 = 0;                                                   \
    if (pfch) {                                                                   \
      kstage((BUF_) ^ 1, (t_ + 1) * 128);                                         \
      vstage((BUF_) ^ 1, (t_ + 1) * 128);                                         \
      mnext0 = maskp[(t_ + 1) * 128];                                             \
      mnext1 = maskp[(t_ + 1) * 128 + 64];                                        \
    }                                                                             \
    const u16* ks = &Ks[(BUF_)][0];                                               \
    const u16* vt = &Vt[(BUF_)][0];                                               \
    f32x4 sc[2][8];                                                               \
    __builtin_amdgcn_s_setprio(1);                                                \
    _Pragma("unroll") for (int n = 0; n < 8; ++n) {                               \
      const s16x8 kf0 = *reinterpret_cast<const s16x8*>(ks + koff[n][0]);         \
      const s16x8 kf1 = *reinterpret_cast<const s16x8*>(ks + koff[n][1]);         \
      f32x4 s0 = {0.f, 0.f, 0.f, 0.f};                                            \
      f32x4 s1 = {0.f, 0.f, 0.f, 0.f};                                            \
      s0 = MFMA16(kf0, qf[0][0], s0);                                             \
      s1 = MFMA16(kf0, qf[1][0], s1);                                             \
      s0 = MFMA16(kf1, qf[0][1], s0);                                             \
      s1 = MFMA16(kf1, qf[1][1], s1);                                             \
      sc[0][n] = s0;                                                              \
      sc[1][n] = s1;                                                              \
    }                                                                             \
    __builtin_amdgcn_s_setprio(0);                                                \
    const unsigned long long mb0 = __ballot(mcur0 != 0);                          \
    const unsigned long long mb1 = __ballot(mcur1 != 0);                          \
    if ((~mb0) | (~mb1)) {                                                        \
      _Pragma("unroll") for (int n = 0; n < 8; ++n) {                             \
        const unsigned long long mb = (n < 4) ? mb0 : mb1;                        \
        const int sh = (n & 3) * 16 + kq * 4;                                     \
        _Pragma("unroll") for (int r = 0; r < 4; ++r) {                           \
          if (!((mb >> (sh + r)) & 1ull)) {                                       \
            sc[0][n][r] = -3.0e38f;                                               \
            sc[1][n][r] = -3.0e38f;                                               \
          }                                                                       \
        }                                                                         \
      }                                                                           \
    }                                                                             \
    union PK { uint32_t u[16]; s16x8 v[4]; } pk[2];                               \
    _Pragma("unroll") for (int g2 = 0; g2 < 2; ++g2) {                            \
      float tm = -1e30f;                                                          \
      _Pragma("unroll") for (int n = 0; n < 8; ++n)                               \
      _Pragma("unroll") for (int r = 0; r < 4; ++r)                               \
          tm = fmaxf(tm, sc[g2][n][r]);                                           \
      tm = fmaxf(tm, __shfl_xor(tm, 16));                                         \
      tm = fmaxf(tm, __shfl_xor(tm, 32));                                         \
      if (!__all(tm <= m_run[g2] + 44.0f)) {                                      \
        const float mnew = fmaxf(m_run[g2], tm);                                  \
        const float fac = exp2f((m_run[g2] - mnew) * Cs);                         \
        m_run[g2] = mnew;                                                         \
        l_run[g2] *= fac;                                                         \
        _Pragma("unroll") for (int m = 0; m < 4; ++m)                             \
        _Pragma("unroll") for (int r = 0; r < 4; ++r) acc[g2][m][r] *= fac;       \
      }                                                                           \
      float rs = 0.f;                                                             \
      const float mneg = -m_run[g2] * Cs;                                         \
      _Pragma("unroll") for (int n = 0; n < 8; ++n)                               \
      _Pragma("unroll") for (int r = 0; r < 4; ++r) {                             \
        const float p = exp2f(fmaf(sc[g2][n][r], Cs, mneg));                      \
        sc[g2][n][r] = p;                                                         \
        rs += p;                                                                  \
      }                                                                           \
      rs += __shfl_xor(rs, 16);                                                   \
      rs += __shfl_xor(rs, 32);                                                   \
      l_run[g2] += rs;                                                            \
      _Pragma("unroll") for (int n = 0; n < 8; ++n) {                             \
        asm("v_cvt_pk_bf16_f32 %0, %1, %2"                                        \
            : "=v"(pk[g2].u[2 * n]) : "v"(sc[g2][n][0]), "v"(sc[g2][n][1]));      \
        asm("v_cvt_pk_bf16_f32 %0, %1, %2"                                        \
            : "=v"(pk[g2].u[2 * n + 1]) : "v"(sc[g2][n][2]), "v"(sc[g2][n][3])); \
      }                                                                           \
    }                                                                             \
    _Pragma("unroll") for (int m = 0; m < 4; ++m) {                               \
      const u16* vr = vt + m * 2048;                                              \
      s16x8 vfr[4];                                                               \
      _Pragma("unroll") for (int c = 0; c < 4; ++c) {                             \
        union VF { s16x4 h[2]; s16x8 v; } vv;                                     \
        vv.h[0] = *reinterpret_cast<const s16x4*>(vr + vbase[2 * c]);             \
        vv.h[1] = *reinterpret_cast<const s16x4*>(vr + vbase[2 * c + 1]);         \
        vfr[c] = vv.v;                                                            \
      }                                                                           \
      __builtin_amdgcn_s_setprio(1);                                              \
      _Pragma("unroll") for (int c = 0; c < 4; ++c) {                             \
        acc[0][m] = MFMA16(vfr[c], pk[0].v[c], acc[0][m]);                        \
        acc[1][m] = MFMA16(vfr[c], pk[1].v[c], acc[1][m]);                        \
      }                                                                           \
      __builtin_amdgcn_s_setprio(0);                                              \
    }                                                                             \
    mcur0 = mnext0;                                                               \
    mcur1 = mnext1;                                                               \
  }

  for (int t = 0; t < NTT_; t += 2) {
    ATTN_TILE(t, 0)
    ATTN_TILE(t + 1, 1)
  }
#undef ATTN_TILE

  // normalize + store O^T -> O (bf16, token-major [BS][D])
#pragma unroll
  for (int g2 = 0; g2 < 2; ++g2) {
    const float rl = 1.0f / l_run[g2];
    u16* op = O + (size_t)(b * S_ + q0 + g2 * 16 + l16) * D_ + h * HD_ + kq * 4;
#pragma unroll
    for (int m = 0; m < 4; ++m) {
      uint2 o;
      o.x = (uint32_t)f2b(acc[g2][m][0] * rl) | ((uint32_t)f2b(acc[g2][m][1] * rl) << 16);
      o.y = (uint32_t)f2b(acc[g2][m][2] * rl) | ((uint32_t)f2b(acc[g2][m][3] * rl) << 16);
      *reinterpret_cast<uint2*>(op + m * 16) = o;
    }
  }
}

// ---------------- launch ----------------
extern "C" void kernel_launch(void* const* d_in, const int* in_sizes, int n_in,
                              void* d_out, int out_size, void* d_ws, size_t ws_size,
                              hipStream_t stream) {
  const float* x = (const float*)d_in[0];
  const int* mask = (const int*)d_in[1];
  const float* Wq = (const float*)d_in[2];
  const float* Wk = (const float*)d_in[3];
  const float* Wv = (const float*)d_in[4];
  const float* Wo = (const float*)d_in[5];

  char* w = (char*)d_ws;
  u16* xb = (u16*)w;    w += (size_t)BS_ * D_ * 2;     // contiguous cvt dst
  u16* Wqkvb = (u16*)w; w += (size_t)QKVS_ * D_ * 2;
  u16* Wob = (u16*)w;   w += (size_t)D_ * D_ * 2;
  u16* QKVw = (u16*)w;  w += (size_t)BS_ * QKVS_ * 2;
  u16* VTw = (u16*)w;   w += (size_t)B_ * KVH_ * HD_ * S_ * 2;
  u16* AOw = (u16*)w;   w += (size_t)BS_ * D_ * 2;

  const int n4tot = (BS_ * D_ + QKVS_ * D_ + D_ * D_) / 4;
  cvt5_kernel<<<dim3(2048), dim3(256), 0, stream>>>(x, Wq, Wk, Wv, Wo, xb, n4tot);

  // fused QKV projection: (4096 x 1536), 64x128 tiles -> 768 blocks (3/CU)
  gemm64<1><<<dim3(QKVS_ / 128, BS_ / 64), dim3(256), 0, stream>>>(xb, Wqkvb, QKVw, BS_, QKVS_, D_);
  // transpose V for direct LDS staging
  vtrans_kernel<<<dim3(S_ / 64, B_ * KVH_), dim3(256), 0, stream>>>(QKVw, VTw);
  // attention: (S/32, B*KVH) blocks of 4 waves, 32 q-rows/wave, KVBLK=128
  attn_kernel<<<dim3(S_ / 32, B_ * KVH_), dim3(256), 0, stream>>>(QKVw, VTw, mask, AOw);
  // output projection -> fp32 d_out, 64x128 tiles -> 512 blocks (2/CU)
  gemm64<0><<<dim3(D_ / 128, BS_ / 64), dim3(256), 0, stream>>>(AOw, Wob, (float*)d_out, BS_, D_, D_);
}

// Round 19
// 119.239 us; speedup vs baseline: 1.3449x; 1.0704x over previous
//
#include <hip/hip_runtime.h>
#include <hip/hip_bf16.h>
#include <stdint.h>

// Problem constants (GroupedQueryAttention: B=2,S=2048,D=1024,H=16,KVH=4)
#define B_    2
#define S_    2048
#define D_    1024
#define H_    16
#define KVH_  4
#define HD_   64
#define REP_  4
#define BS_   (B_ * S_)        // 4096 tokens
#define KVD_  256
#define QKVS_ 1536             // fused QKV row stride: Q(1024) | K(256) | V(256)
#define NTT_  (S_ / 128)       // 16 KV tiles of 128

typedef unsigned short u16;
typedef short s16x4 __attribute__((ext_vector_type(4)));
typedef short s16x8 __attribute__((ext_vector_type(8)));
typedef float f32x4 __attribute__((ext_vector_type(4)));

typedef const __attribute__((address_space(1))) void* gvp;
typedef __attribute__((address_space(3))) void* lvp;

#define MFMA16(a, b, c) __builtin_amdgcn_mfma_f32_16x16x32_bf16((a), (b), (c), 0, 0, 0)

__device__ __forceinline__ u16 f2b(float f) {  // RNE f32->bf16 (finite inputs)
  uint32_t u = __float_as_uint(f);
  u += 0x7fffu + ((u >> 16) & 1u);
  return (u16)(u >> 16);
}

// XOR swizzles: 64-wide rows (8 x 16B slots) and 128-wide rows (16 slots).
__device__ __forceinline__ int swz64(int row, int slot) {
  return slot ^ (row & 7) ^ ((row >> 3) & 7);
}
__device__ __forceinline__ int swz128(int row, int slot) {
  return slot ^ (row & 15);
}

// ---------------- fused f32 -> bf16 conversion over 5 segments ----------------
#define N0_ (BS_ * D_ / 4)
#define N1_ (D_ * D_ / 4)
#define N2_ (KVD_ * D_ / 4)
__global__ void cvt5_kernel(const float* __restrict__ s0, const float* __restrict__ s1,
                            const float* __restrict__ s2, const float* __restrict__ s3,
                            const float* __restrict__ s4, u16* __restrict__ dst, int n4tot) {
  for (int i = blockIdx.x * blockDim.x + threadIdx.x; i < n4tot;
       i += gridDim.x * blockDim.x) {
    const float* src;
    int j = i;
    if (j < N0_) src = s0;
    else if ((j -= N0_) < N1_) src = s1;
    else if ((j -= N1_) < N2_) src = s2;
    else if ((j -= N2_) < N2_) src = s3;
    else { j -= N2_; src = s4; }
    const float4 v = reinterpret_cast<const float4*>(src)[j];
    uint2 o;
    o.x = (uint32_t)f2b(v.x) | ((uint32_t)f2b(v.y) << 16);
    o.y = (uint32_t)f2b(v.z) | ((uint32_t)f2b(v.w) << 16);
    reinterpret_cast<uint2*>(dst)[i] = o;
  }
}

// ---------------- bf16 GEMM, C = A(MxK) * B(NxK)^T, 64x128 tile, BK=64 ----------------
// swz64 both-sides LDS swizzle (pre-swizzled global_load_lds source + involution
// reads) -> conflict-free ds_read_b128. 2 barriers per 64-K. XCD-bijective grid.
template <int OUT_BF16>
__global__ __launch_bounds__(256) void gemm64(const u16* __restrict__ A,
                                              const u16* __restrict__ Bw,
                                              void* __restrict__ Cout,
                                              int M, int N, int K) {
  __shared__ u16 As[64 * 64];
  __shared__ u16 Bs[128 * 64];
  const int tid = threadIdx.x;
  const int lane = tid & 63;
  const int wid = tid >> 6;
  const int l16 = lane & 15;
  const int kq = lane >> 4;
  // XCD swizzle: hw-blocks on one XCD (bid0 mod 8) get a contiguous logical chunk
  const int nwg = gridDim.x * gridDim.y;
  const int bid0 = blockIdx.y * gridDim.x + blockIdx.x;
  const int bid = (bid0 & 7) * (nwg >> 3) + (bid0 >> 3);
  const int bm = (bid / gridDim.x) * 64;
  const int bn = (bid % gridDim.x) * 128;
  const int wr = (wid >> 1) * 32;
  const int wc = (wid & 1) * 64;

  // staging geometry (pre-swizzled source cols, linear LDS dst)
  int arow[2], acol[2], brow[4], bcol[4], sdst[4];
#pragma unroll
  for (int i = 0; i < 4; ++i) {
    const int e = (i * 256 + tid) * 8;
    const int row = e >> 6;
    const int col = swz64(row, (e >> 3) & 7) * 8;
    sdst[i] = e;
    if (i < 2) { arow[i] = row; acol[i] = col; }
    brow[i] = row;
    bcol[i] = col;
  }
  // frag read offsets (involution)
  int aoff[2][2], boff[4][2];
#pragma unroll
  for (int m = 0; m < 2; ++m)
#pragma unroll
    for (int kk = 0; kk < 2; ++kk) {
      const int row = wr + m * 16 + l16;
      aoff[m][kk] = row * 64 + swz64(row, kk * 4 + kq) * 8;
    }
#pragma unroll
  for (int n = 0; n < 4; ++n)
#pragma unroll
    for (int kk = 0; kk < 2; ++kk) {
      const int row = wc + n * 16 + l16;
      boff[n][kk] = row * 64 + swz64(row, kk * 4 + kq) * 8;
    }

  f32x4 acc[2][4] = {};

  for (int kt = 0; kt < K; kt += 64) {
    __syncthreads();
#pragma unroll
    for (int i = 0; i < 2; ++i)
      __builtin_amdgcn_global_load_lds((gvp)(A + (size_t)(bm + arow[i]) * K + kt + acol[i]),
                                       (lvp)(&As[sdst[i]]), 16, 0, 0);
#pragma unroll
    for (int i = 0; i < 4; ++i)
      __builtin_amdgcn_global_load_lds((gvp)(Bw + (size_t)(bn + brow[i]) * K + kt + bcol[i]),
                                       (lvp)(&Bs[sdst[i]]), 16, 0, 0);
    __syncthreads();

#pragma unroll
    for (int kk = 0; kk < 2; ++kk) {
      s16x8 af[2], bfr[4];
#pragma unroll
      for (int m = 0; m < 2; ++m)
        af[m] = *reinterpret_cast<const s16x8*>(&As[aoff[m][kk]]);
#pragma unroll
      for (int n = 0; n < 4; ++n)
        bfr[n] = *reinterpret_cast<const s16x8*>(&Bs[boff[n][kk]]);
#pragma unroll
      for (int m = 0; m < 2; ++m)
#pragma unroll
        for (int n = 0; n < 4; ++n)
          acc[m][n] = MFMA16(af[m], bfr[n], acc[m][n]);
    }
  }

#pragma unroll
  for (int m = 0; m < 2; ++m) {
    const int row0 = bm + wr + m * 16 + kq * 4;
#pragma unroll
    for (int n = 0; n < 4; ++n) {
      const int col = bn + wc + n * 16 + l16;
#pragma unroll
      for (int r = 0; r < 4; ++r) {
        if (OUT_BF16) {
          ((u16*)Cout)[(size_t)(row0 + r) * N + col] = f2b(acc[m][n][r]);
        } else {
          ((float*)Cout)[(size_t)(row0 + r) * N + col] = acc[m][n][r];
        }
      }
    }
  }
}

// ---------------- V transpose: QKV V-part -> VT[(b*4+g)*64 + d][s] ----------------
__global__ __launch_bounds__(256) void vtrans_kernel(const u16* __restrict__ QKV,
                                                     u16* __restrict__ VT) {
  __shared__ u16 T[64][72];
  const int tid = threadIdx.x;
  const int s0 = blockIdx.x * 64;
  const int bg = blockIdx.y;
  const int b = bg >> 2;
  const int g = bg & 3;
  const int r = tid >> 2;
  const int c0 = (tid & 3) * 16;
  const u16* src = QKV + (size_t)(b * S_ + s0 + r) * QKVS_ + D_ + KVD_ + g * HD_ + c0;
  const uint4 a = reinterpret_cast<const uint4*>(src)[0];
  const uint4 bq = reinterpret_cast<const uint4*>(src)[1];
  *reinterpret_cast<uint4*>(&T[r][c0]) = a;
  *reinterpret_cast<uint4*>(&T[r][c0 + 8]) = bq;
  __syncthreads();
  const int d = tid >> 2;
  u16 tmp[16];
#pragma unroll
  for (int j = 0; j < 16; ++j) tmp[j] = T[c0 + j][d];
  u16* dst = VT + ((size_t)bg * 64 + d) * S_ + s0 + c0;
  *reinterpret_cast<uint4*>(dst) = *reinterpret_cast<const uint4*>(&tmp[0]);
  *reinterpret_cast<uint4*>(dst + 8) = *reinterpret_cast<const uint4*>(&tmp[8]);
}

// ---------------- flash attention (GQA): zero-shuffle PV, KVBLK=128 ----------------
__global__ __launch_bounds__(256, 2) void attn_kernel(const u16* __restrict__ QKV,
                                                      const u16* __restrict__ VT,
                                                      const int* __restrict__ mask,
                                                      u16* __restrict__ O) {
  __shared__ u16 Ks[2][128 * 64];      // K rows, 64-wide swizzled
  __shared__ u16 Vt[2][64 * 128];      // V^T rows (d), 128-wide swizzled

  const int tid = threadIdx.x;
  const int lane = tid & 63;
  const int wid = tid >> 6;            // 0..3 = head within group
  const int l16 = lane & 15;
  const int kq = lane >> 4;            // 0..3
  const int bg = blockIdx.y;
  const int b = bg >> 2;               // / KVH
  const int g = bg & 3;
  const int h = g * REP_ + wid;
  const int q0 = blockIdx.x * 32;
  const u16* kv_base = QKV + (size_t)b * S_ * QKVS_ + D_ + g * HD_;  // K cols
  const u16* vt_base = VT + (size_t)bg * 64 * S_;                     // V^T rows
  const int* maskp = mask + b * S_ + lane;
  const float Cs = 0.18033688011112042f;  // SCALE * log2(e)

  // ---- precomputed per-thread LDS element offsets (loop-invariant) ----
  int koff[8][2];
#pragma unroll
  for (int n = 0; n < 8; ++n)
#pragma unroll
    for (int c = 0; c < 2; ++c) {
      const int row = n * 16 + l16;
      koff[n][c] = row * 64 + swz64(row, c * 4 + kq) * 8;
    }
  const int hs = kq >> 1;
  const int bo = 4 * (kq & 1);
  int vbase[8];                        // voff = vbase[j] + m*2048  (drow&15 == l16)
#pragma unroll
  for (int c = 0; c < 4; ++c) {
    vbase[2 * c] = l16 * 128 + swz128(l16, 4 * c + hs) * 8 + bo;
    vbase[2 * c + 1] = l16 * 128 + swz128(l16, 4 * c + 2 + hs) * 8 + bo;
  }
  int kst_src[4], vst_src[4], st_dst[4];
#pragma unroll
  for (int i = 0; i < 4; ++i) {
    const int e = (i * 256 + tid) * 8;
    st_dst[i] = e;
    const int krow = e >> 6;
    kst_src[i] = krow * QKVS_ + swz64(krow, (e >> 3) & 7) * 8;   // + kv0*QKVS_
    const int vrow = e >> 7;
    vst_src[i] = vrow * S_ + swz128(vrow, (e >> 3) & 15) * 8;    // + kv0
  }

  auto kstage = [&](int buf, int kv0) {
#pragma unroll
    for (int i = 0; i < 4; ++i)
      __builtin_amdgcn_global_load_lds(
          (gvp)(kv_base + (size_t)kv0 * QKVS_ + kst_src[i]),
          (lvp)(&Ks[buf][st_dst[i]]), 16, 0, 0);
  };
  auto vstage = [&](int buf, int kv0) {
#pragma unroll
    for (int i = 0; i < 4; ++i)
      __builtin_amdgcn_global_load_lds(
          (gvp)(vt_base + kv0 + vst_src[i]),
          (lvp)(&Vt[buf][st_dst[i]]), 16, 0, 0);
  };

  // Q B-frags: qf[g2][c] = Q[q0+g2*16+l16][c*32+kq*8..]
  s16x8 qf[2][2];
#pragma unroll
  for (int g2 = 0; g2 < 2; ++g2) {
    const u16* qp = QKV + (size_t)(b * S_ + q0 + g2 * 16 + l16) * QKVS_ + h * HD_ + kq * 8;
    qf[g2][0] = *reinterpret_cast<const s16x8*>(qp);
    qf[g2][1] = *reinterpret_cast<const s16x8*>(qp + 32);
  }

  // prologue: stage tile 0 into buf 0; mask tile 0 into regs
  kstage(0, 0);
  vstage(0, 0);
  int mcur0 = maskp[0];
  int mcur1 = maskp[64];

  float m_run[2] = {-1e30f, -1e30f}, l_run[2] = {0.f, 0.f};
  f32x4 acc[2][4] = {};                // O^T per group: row d=m*16+kq*4+r, col q=l16

#define ATTN_TILE(T_, BUF_)                                                       \
  {                                                                               \
    const int t_ = (T_);                                                          \
    __syncthreads();                                                              \
    const bool pfch = (t_ + 1 < NTT_);                                            \
    int mnext0 = 0, mnext1 = 0;                                                   \
    if (pfch) {                                                                   \
      kstage((BUF_) ^ 1, (t_ + 1) * 128);                                         \
      vstage((BUF_) ^ 1, (t_ + 1) * 128);                                         \
      mnext0 = maskp[(t_ + 1) * 128];                                             \
      mnext1 = maskp[(t_ + 1) * 128 + 64];                                        \
    }                                                                             \
    const u16* ks = &Ks[(BUF_)][0];                                               \
    const u16* vt = &Vt[(BUF_)][0];                                               \
    f32x4 sc[2][8];                                                               \
    __builtin_amdgcn_s_setprio(1);                                                \
    _Pragma("unroll") for (int n = 0; n < 8; ++n) {                               \
      const s16x8 kf0 = *reinterpret_cast<const s16x8*>(ks + koff[n][0]);         \
      const s16x8 kf1 = *reinterpret_cast<const s16x8*>(ks + koff[n][1]);         \
      f32x4 s0 = {0.f, 0.f, 0.f, 0.f};                                            \
      f32x4 s1 = {0.f, 0.f, 0.f, 0.f};                                            \
      s0 = MFMA16(kf0, qf[0][0], s0);                                             \
      s1 = MFMA16(kf0, qf[1][0], s1);                                             \
      s0 = MFMA16(kf1, qf[0][1], s0);                                             \
      s1 = MFMA16(kf1, qf[1][1], s1);                                             \
      sc[0][n] = s0;                                                              \
      sc[1][n] = s1;                                                              \
    }                                                                             \
    __builtin_amdgcn_s_setprio(0);                                                \
    const unsigned long long mb0 = __ballot(mcur0 != 0);                          \
    const unsigned long long mb1 = __ballot(mcur1 != 0);                          \
    if ((~mb0) | (~mb1)) {                                                        \
      _Pragma("unroll") for (int n = 0; n < 8; ++n) {                             \
        const unsigned long long mb = (n < 4) ? mb0 : mb1;                        \
        const int sh = (n & 3) * 16 + kq * 4;                                     \
        _Pragma("unroll") for (int r = 0; r < 4; ++r) {                           \
          if (!((mb >> (sh + r)) & 1ull)) {                                       \
            sc[0][n][r] = -3.0e38f;                                               \
            sc[1][n][r] = -3.0e38f;                                               \
          }                                                                       \
        }                                                                         \
      }                                                                           \
    }                                                                             \
    union PK { uint32_t u[16]; s16x8 v[4]; } pk[2];                               \
    _Pragma("unroll") for (int g2 = 0; g2 < 2; ++g2) {                            \
      float tm = -1e30f;                                                          \
      _Pragma("unroll") for (int n = 0; n < 8; ++n)                               \
      _Pragma("unroll") for (int r = 0; r < 4; ++r)                               \
          tm = fmaxf(tm, sc[g2][n][r]);                                           \
      tm = fmaxf(tm, __shfl_xor(tm, 16));                                         \
      tm = fmaxf(tm, __shfl_xor(tm, 32));                                         \
      if (!__all(tm <= m_run[g2] + 44.0f)) {                                      \
        const float mnew = fmaxf(m_run[g2], tm);                                  \
        const float fac = exp2f((m_run[g2] - mnew) * Cs);                         \
        m_run[g2] = mnew;                                                         \
        l_run[g2] *= fac;                                                         \
        _Pragma("unroll") for (int m = 0; m < 4; ++m)                             \
        _Pragma("unroll") for (int r = 0; r < 4; ++r) acc[g2][m][r] *= fac;       \
      }                                                                           \
      float rs = 0.f;                                                             \
      const float mneg = -m_run[g2] * Cs;                                         \
      _Pragma("unroll") for (int n = 0; n < 8; ++n)                               \
      _Pragma("unroll") for (int r = 0; r < 4; ++r) {                             \
        const float p = exp2f(fmaf(sc[g2][n][r], Cs, mneg));                      \
        sc[g2][n][r] = p;                                                         \
        rs += p;                                                                  \
      }                                                                           \
      rs += __shfl_xor(rs, 16);                                                   \
      rs += __shfl_xor(rs, 32);                                                   \
      l_run[g2] += rs;                                                            \
      _Pragma("unroll") for (int n = 0; n < 8; ++n) {                             \
        asm("v_cvt_pk_bf16_f32 %0, %1, %2"                                        \
            : "=v"(pk[g2].u[2 * n]) : "v"(sc[g2][n][0]), "v"(sc[g2][n][1]));      \
        asm("v_cvt_pk_bf16_f32 %0, %1, %2"                                        \
            : "=v"(pk[g2].u[2 * n + 1]) : "v"(sc[g2][n][2]), "v"(sc[g2][n][3])); \
      }                                                                           \
    }                                                                             \
    _Pragma("unroll") for (int m = 0; m < 4; ++m) {                               \
      const u16* vr = vt + m * 2048;                                              \
      s16x8 vfr[4];                                                               \
      _Pragma("unroll") for (int c = 0; c < 4; ++c) {                             \
        union VF { s16x4 h[2]; s16x8 v; } vv;                                     \
        vv.h[0] = *reinterpret_cast<const s16x4*>(vr + vbase[2 * c]);             \
        vv.h[1] = *reinterpret_cast<const s16x4*>(vr + vbase[2 * c + 1]);         \
        vfr[c] = vv.v;                                                            \
      }                                                                           \
      __builtin_amdgcn_s_setprio(1);                                              \
      _Pragma("unroll") for (int c = 0; c < 4; ++c) {                             \
        acc[0][m] = MFMA16(vfr[c], pk[0].v[c], acc[0][m]);                        \
        acc[1][m] = MFMA16(vfr[c], pk[1].v[c], acc[1][m]);                        \
      }                                                                           \
      __builtin_amdgcn_s_setprio(0);                                              \
    }                                                                             \
    mcur0 = mnext0;                                                               \
    mcur1 = mnext1;                                                               \
  }

  for (int t = 0; t < NTT_; t += 2) {
    ATTN_TILE(t, 0)
    ATTN_TILE(t + 1, 1)
  }
#undef ATTN_TILE

  // normalize + store O^T -> O (bf16, token-major [BS][D])
#pragma unroll
  for (int g2 = 0; g2 < 2; ++g2) {
    const float rl = 1.0f / l_run[g2];
    u16* op = O + (size_t)(b * S_ + q0 + g2 * 16 + l16) * D_ + h * HD_ + kq * 4;
#pragma unroll
    for (int m = 0; m < 4; ++m) {
      uint2 o;
      o.x = (uint32_t)f2b(acc[g2][m][0] * rl) | ((uint32_t)f2b(acc[g2][m][1] * rl) << 16);
      o.y = (uint32_t)f2b(acc[g2][m][2] * rl) | ((uint32_t)f2b(acc[g2][m][3] * rl) << 16);
      *reinterpret_cast<uint2*>(op + m * 16) = o;
    }
  }
}

// ---------------- launch ----------------
extern "C" void kernel_launch(void* const* d_in, const int* in_sizes, int n_in,
                              void* d_out, int out_size, void* d_ws, size_t ws_size,
                              hipStream_t stream) {
  const float* x = (const float*)d_in[0];
  const int* mask = (const int*)d_in[1];
  const float* Wq = (const float*)d_in[2];
  const float* Wk = (const float*)d_in[3];
  const float* Wv = (const float*)d_in[4];
  const float* Wo = (const float*)d_in[5];

  char* w = (char*)d_ws;
  u16* xb = (u16*)w;    w += (size_t)BS_ * D_ * 2;     // contiguous cvt dst
  u16* Wqkvb = (u16*)w; w += (size_t)QKVS_ * D_ * 2;
  u16* Wob = (u16*)w;   w += (size_t)D_ * D_ * 2;
  u16* QKVw = (u16*)w;  w += (size_t)BS_ * QKVS_ * 2;
  u16* VTw = (u16*)w;   w += (size_t)B_ * KVH_ * HD_ * S_ * 2;
  u16* AOw = (u16*)w;   w += (size_t)BS_ * D_ * 2;

  const int n4tot = (BS_ * D_ + QKVS_ * D_ + D_ * D_) / 4;
  cvt5_kernel<<<dim3(2048), dim3(256), 0, stream>>>(x, Wq, Wk, Wv, Wo, xb, n4tot);

  // fused QKV projection: (4096 x 1536), 64x128 tiles -> 768 blocks (3/CU)
  gemm64<1><<<dim3(QKVS_ / 128, BS_ / 64), dim3(256), 0, stream>>>(xb, Wqkvb, QKVw, BS_, QKVS_, D_);
  // transpose V for direct LDS staging
  vtrans_kernel<<<dim3(S_ / 64, B_ * KVH_), dim3(256), 0, stream>>>(QKVw, VTw);
  // attention: (S/32, B*KVH) blocks of 4 waves, 32 q-rows/wave, KVBLK=128
  attn_kernel<<<dim3(S_ / 32, B_ * KVH_), dim3(256), 0, stream>>>(QKVw, VTw, mask, AOw);
  // output projection -> fp32 d_out, 64x128 tiles -> 512 blocks (2/CU)
  gemm64<0><<<dim3(D_ / 128, BS_ / 64), dim3(256), 0, stream>>>(AOw, Wob, (float*)d_out, BS_, D_, D_);
}

// Round 20
// 115.611 us; speedup vs baseline: 1.3871x; 1.0314x over previous
//
#include <hip/hip_runtime.h>
#include <hip/hip_bf16.h>
#include <stdint.h>

// Problem constants (GroupedQueryAttention: B=2,S=2048,D=1024,H=16,KVH=4)
#define B_    2
#define S_    2048
#define D_    1024
#define H_    16
#define KVH_  4
#define HD_   64
#define REP_  4
#define BS_   (B_ * S_)        // 4096 tokens
#define KVD_  256
#define QKVS_ 1536             // fused QKV row stride: Q(1024) | K(256) | V(256)
#define NTT_  (S_ / 128)       // 16 KV tiles of 128
#define VSPLIT_ (D_ + KVD_)    // 1280: V columns start here (block-aligned)

typedef unsigned short u16;
typedef short s16x4 __attribute__((ext_vector_type(4)));
typedef short s16x8 __attribute__((ext_vector_type(8)));
typedef float f32x4 __attribute__((ext_vector_type(4)));

typedef const __attribute__((address_space(1))) void* gvp;
typedef __attribute__((address_space(3))) void* lvp;

#define MFMA16(a, b, c) __builtin_amdgcn_mfma_f32_16x16x32_bf16((a), (b), (c), 0, 0, 0)

__device__ __forceinline__ u16 f2b(float f) {  // RNE f32->bf16 (finite inputs)
  uint32_t u = __float_as_uint(f);
  u += 0x7fffu + ((u >> 16) & 1u);
  return (u16)(u >> 16);
}

// XOR swizzles: 64-wide rows (8 x 16B slots) and 128-wide rows (16 slots).
__device__ __forceinline__ int swz64(int row, int slot) {
  return slot ^ (row & 7) ^ ((row >> 3) & 7);
}
__device__ __forceinline__ int swz128(int row, int slot) {
  return slot ^ (row & 15);
}

// ---------------- fused f32 -> bf16 conversion over 5 segments ----------------
#define N0_ (BS_ * D_ / 4)
#define N1_ (D_ * D_ / 4)
#define N2_ (KVD_ * D_ / 4)
__global__ void cvt5_kernel(const float* __restrict__ s0, const float* __restrict__ s1,
                            const float* __restrict__ s2, const float* __restrict__ s3,
                            const float* __restrict__ s4, u16* __restrict__ dst, int n4tot) {
  for (int i = blockIdx.x * blockDim.x + threadIdx.x; i < n4tot;
       i += gridDim.x * blockDim.x) {
    const float* src;
    int j = i;
    if (j < N0_) src = s0;
    else if ((j -= N0_) < N1_) src = s1;
    else if ((j -= N1_) < N2_) src = s2;
    else if ((j -= N2_) < N2_) src = s3;
    else { j -= N2_; src = s4; }
    const float4 v = reinterpret_cast<const float4*>(src)[j];
    uint2 o;
    o.x = (uint32_t)f2b(v.x) | ((uint32_t)f2b(v.y) << 16);
    o.y = (uint32_t)f2b(v.z) | ((uint32_t)f2b(v.w) << 16);
    reinterpret_cast<uint2*>(dst)[i] = o;
  }
}

// ---------------- bf16 GEMM, C = A(MxK) * B(NxK)^T, 64x128 tile, BK=64 ----------------
// Double-buffered staging (attn-verified pattern): issue next K-tile after the
// barrier, compute current, 1 barrier/step. swz64 both-sides LDS swizzle.
// WRITE_VT: V-columns (>= VSPLIT_) written TRANSPOSED to VT (fused vtrans).
template <int OUT_BF16, int WRITE_VT>
__global__ __launch_bounds__(256) void gemm64(const u16* __restrict__ A,
                                              const u16* __restrict__ Bw,
                                              void* __restrict__ Cout,
                                              u16* __restrict__ VT,
                                              int M, int N, int K) {
  __shared__ u16 As[2][64 * 64];
  __shared__ u16 Bs[2][128 * 64];
  const int tid = threadIdx.x;
  const int lane = tid & 63;
  const int wid = tid >> 6;
  const int l16 = lane & 15;
  const int kq = lane >> 4;
  // XCD swizzle: hw-blocks on one XCD (bid0 mod 8) get a contiguous logical chunk
  const int nwg = gridDim.x * gridDim.y;
  const int bid0 = blockIdx.y * gridDim.x + blockIdx.x;
  const int bid = (bid0 & 7) * (nwg >> 3) + (bid0 >> 3);
  const int bm = (bid / gridDim.x) * 64;
  const int bn = (bid % gridDim.x) * 128;
  const int wr = (wid >> 1) * 32;
  const int wc = (wid & 1) * 64;

  // staging geometry (pre-swizzled source cols, linear LDS dst)
  int arow[2], acol[2], brow[4], bcol[4], sdst[4];
#pragma unroll
  for (int i = 0; i < 4; ++i) {
    const int e = (i * 256 + tid) * 8;
    const int row = e >> 6;
    const int col = swz64(row, (e >> 3) & 7) * 8;
    sdst[i] = e;
    if (i < 2) { arow[i] = row; acol[i] = col; }
    brow[i] = row;
    bcol[i] = col;
  }
  // frag read offsets (involution)
  int aoff[2][2], boff[4][2];
#pragma unroll
  for (int m = 0; m < 2; ++m)
#pragma unroll
    for (int kk = 0; kk < 2; ++kk) {
      const int row = wr + m * 16 + l16;
      aoff[m][kk] = row * 64 + swz64(row, kk * 4 + kq) * 8;
    }
#pragma unroll
  for (int n = 0; n < 4; ++n)
#pragma unroll
    for (int kk = 0; kk < 2; ++kk) {
      const int row = wc + n * 16 + l16;
      boff[n][kk] = row * 64 + swz64(row, kk * 4 + kq) * 8;
    }

  auto stage = [&](int buf, int kt) {
#pragma unroll
    for (int i = 0; i < 2; ++i)
      __builtin_amdgcn_global_load_lds((gvp)(A + (size_t)(bm + arow[i]) * K + kt + acol[i]),
                                       (lvp)(&As[buf][sdst[i]]), 16, 0, 0);
#pragma unroll
    for (int i = 0; i < 4; ++i)
      __builtin_amdgcn_global_load_lds((gvp)(Bw + (size_t)(bn + brow[i]) * K + kt + bcol[i]),
                                       (lvp)(&Bs[buf][sdst[i]]), 16, 0, 0);
  };

  f32x4 acc[2][4] = {};
  stage(0, 0);
  int cur = 0;

  for (int kt = 0; kt < K; kt += 64) {
    __syncthreads();                   // buf[cur] ready (drains in-flight loads)
    if (kt + 64 < K) stage(cur ^ 1, kt + 64);

#pragma unroll
    for (int kk = 0; kk < 2; ++kk) {
      s16x8 af[2], bfr[4];
#pragma unroll
      for (int m = 0; m < 2; ++m)
        af[m] = *reinterpret_cast<const s16x8*>(&As[cur][aoff[m][kk]]);
#pragma unroll
      for (int n = 0; n < 4; ++n)
        bfr[n] = *reinterpret_cast<const s16x8*>(&Bs[cur][boff[n][kk]]);
#pragma unroll
      for (int m = 0; m < 2; ++m)
#pragma unroll
        for (int n = 0; n < 4; ++n)
          acc[m][n] = MFMA16(af[m], bfr[n], acc[m][n]);
    }
    cur ^= 1;
  }

  if (WRITE_VT && bn >= VSPLIT_) {
    // V block: write transposed to VT[((b*4+g)*64+d)][s]; 4 consecutive tokens
    // per (m,n) = 8B contiguous store.
#pragma unroll
    for (int m = 0; m < 2; ++m) {
      const int row0 = bm + wr + m * 16 + kq * 4;   // token row (4 consecutive)
      const int b = row0 >> 11;
      const int s = row0 & (S_ - 1);
#pragma unroll
      for (int n = 0; n < 4; ++n) {
        const int off = bn - VSPLIT_ + wc + n * 16 + l16;
        const int g = off >> 6;
        const int d = off & 63;
        uint2 o;
        o.x = (uint32_t)f2b(acc[m][n][0]) | ((uint32_t)f2b(acc[m][n][1]) << 16);
        o.y = (uint32_t)f2b(acc[m][n][2]) | ((uint32_t)f2b(acc[m][n][3]) << 16);
        *reinterpret_cast<uint2*>(&VT[((size_t)(b * 4 + g) * 64 + d) * S_ + s]) = o;
      }
    }
    return;
  }

#pragma unroll
  for (int m = 0; m < 2; ++m) {
    const int row0 = bm + wr + m * 16 + kq * 4;
#pragma unroll
    for (int n = 0; n < 4; ++n) {
      const int col = bn + wc + n * 16 + l16;
#pragma unroll
      for (int r = 0; r < 4; ++r) {
        if (OUT_BF16) {
          ((u16*)Cout)[(size_t)(row0 + r) * N + col] = f2b(acc[m][n][r]);
        } else {
          ((float*)Cout)[(size_t)(row0 + r) * N + col] = acc[m][n][r];
        }
      }
    }
  }
}

// ---------------- flash attention (GQA): zero-shuffle PV, KVBLK=128 ----------------
__global__ __launch_bounds__(256, 2) void attn_kernel(const u16* __restrict__ QKV,
                                                      const u16* __restrict__ VT,
                                                      const int* __restrict__ mask,
                                                      u16* __restrict__ O) {
  __shared__ u16 Ks[2][128 * 64];      // K rows, 64-wide swizzled
  __shared__ u16 Vt[2][64 * 128];      // V^T rows (d), 128-wide swizzled

  const int tid = threadIdx.x;
  const int lane = tid & 63;
  const int wid = tid >> 6;            // 0..3 = head within group
  const int l16 = lane & 15;
  const int kq = lane >> 4;            // 0..3
  const int bg = blockIdx.y;
  const int b = bg >> 2;               // / KVH
  const int g = bg & 3;
  const int h = g * REP_ + wid;
  const int q0 = blockIdx.x * 32;
  const u16* kv_base = QKV + (size_t)b * S_ * QKVS_ + D_ + g * HD_;  // K cols
  const u16* vt_base = VT + (size_t)bg * 64 * S_;                     // V^T rows
  const int* maskp = mask + b * S_ + lane;
  const float Cs = 0.18033688011112042f;  // SCALE * log2(e)

  // ---- precomputed per-thread LDS element offsets (loop-invariant) ----
  int koff[8][2];
#pragma unroll
  for (int n = 0; n < 8; ++n)
#pragma unroll
    for (int c = 0; c < 2; ++c) {
      const int row = n * 16 + l16;
      koff[n][c] = row * 64 + swz64(row, c * 4 + kq) * 8;
    }
  const int hs = kq >> 1;
  const int bo = 4 * (kq & 1);
  int vbase[8];                        // voff = vbase[j] + m*2048  (drow&15 == l16)
#pragma unroll
  for (int c = 0; c < 4; ++c) {
    vbase[2 * c] = l16 * 128 + swz128(l16, 4 * c + hs) * 8 + bo;
    vbase[2 * c + 1] = l16 * 128 + swz128(l16, 4 * c + 2 + hs) * 8 + bo;
  }
  int kst_src[4], vst_src[4], st_dst[4];
#pragma unroll
  for (int i = 0; i < 4; ++i) {
    const int e = (i * 256 + tid) * 8;
    st_dst[i] = e;
    const int krow = e >> 6;
    kst_src[i] = krow * QKVS_ + swz64(krow, (e >> 3) & 7) * 8;   // + kv0*QKVS_
    const int vrow = e >> 7;
    vst_src[i] = vrow * S_ + swz128(vrow, (e >> 3) & 15) * 8;    // + kv0
  }

  auto kstage = [&](int buf, int kv0) {
#pragma unroll
    for (int i = 0; i < 4; ++i)
      __builtin_amdgcn_global_load_lds(
          (gvp)(kv_base + (size_t)kv0 * QKVS_ + kst_src[i]),
          (lvp)(&Ks[buf][st_dst[i]]), 16, 0, 0);
  };
  auto vstage = [&](int buf, int kv0) {
#pragma unroll
    for (int i = 0; i < 4; ++i)
      __builtin_amdgcn_global_load_lds(
          (gvp)(vt_base + kv0 + vst_src[i]),
          (lvp)(&Vt[buf][st_dst[i]]), 16, 0, 0);
  };

  // Q B-frags: qf[g2][c] = Q[q0+g2*16+l16][c*32+kq*8..]
  s16x8 qf[2][2];
#pragma unroll
  for (int g2 = 0; g2 < 2; ++g2) {
    const u16* qp = QKV + (size_t)(b * S_ + q0 + g2 * 16 + l16) * QKVS_ + h * HD_ + kq * 8;
    qf[g2][0] = *reinterpret_cast<const s16x8*>(qp);
    qf[g2][1] = *reinterpret_cast<const s16x8*>(qp + 32);
  }

  // prologue: stage tile 0 into buf 0; mask tile 0 into regs
  kstage(0, 0);
  vstage(0, 0);
  int mcur0 = maskp[0];
  int mcur1 = maskp[64];

  float m_run[2] = {-1e30f, -1e30f}, l_run[2] = {0.f, 0.f};
  f32x4 acc[2][4] = {};                // O^T per group: row d=m*16+kq*4+r, col q=l16

#define ATTN_TILE(T_, BUF_)                                                       \
  {                                                                               \
    const int t_ = (T_);                                                          \
    __syncthreads();                                                              \
    const bool pfch = (t_ + 1 < NTT_);                                            \
    int mnext0 = 0, mnext1 = 0;                                                   \
    if (pfch) {                                                                   \
      kstage((BUF_) ^ 1, (t_ + 1) * 128);                                         \
      vstage((BUF_) ^ 1, (t_ + 1) * 128);                                         \
      mnext0 = maskp[(t_ + 1) * 128];                                             \
      mnext1 = maskp[(t_ + 1) * 128 + 64];                                        \
    }                                                                             \
    const u16* ks = &Ks[(BUF_)][0];                                               \
    const u16* vt = &Vt[(BUF_)][0];                                               \
    f32x4 sc[2][8];                                                               \
    __builtin_amdgcn_s_setprio(1);                                                \
    _Pragma("unroll") for (int n = 0; n < 8; ++n) {                               \
      const s16x8 kf0 = *reinterpret_cast<const s16x8*>(ks + koff[n][0]);         \
      const s16x8 kf1 = *reinterpret_cast<const s16x8*>(ks + koff[n][1]);         \
      f32x4 s0 = {0.f, 0.f, 0.f, 0.f};                                            \
      f32x4 s1 = {0.f, 0.f, 0.f, 0.f};                                            \
      s0 = MFMA16(kf0, qf[0][0], s0);                                             \
      s1 = MFMA16(kf0, qf[1][0], s1);                                             \
      s0 = MFMA16(kf1, qf[0][1], s0);                                             \
      s1 = MFMA16(kf1, qf[1][1], s1);                                             \
      sc[0][n] = s0;                                                              \
      sc[1][n] = s1;                                                              \
    }                                                                             \
    __builtin_amdgcn_s_setprio(0);                                                \
    const unsigned long long mb0 = __ballot(mcur0 != 0);                          \
    const unsigned long long mb1 = __ballot(mcur1 != 0);                          \
    if ((~mb0) | (~mb1)) {                                                        \
      _Pragma("unroll") for (int n = 0; n < 8; ++n) {                             \
        const unsigned long long mb = (n < 4) ? mb0 : mb1;                        \
        const int sh = (n & 3) * 16 + kq * 4;                                     \
        _Pragma("unroll") for (int r = 0; r < 4; ++r) {                           \
          if (!((mb >> (sh + r)) & 1ull)) {                                       \
            sc[0][n][r] = -3.0e38f;                                               \
            sc[1][n][r] = -3.0e38f;                                               \
          }                                                                       \
        }                                                                         \
      }                                                                           \
    }                                                                             \
    union PK { uint32_t u[16]; s16x8 v[4]; } pk[2];                               \
    _Pragma("unroll") for (int g2 = 0; g2 < 2; ++g2) {                            \
      float tm = -1e30f;                                                          \
      _Pragma("unroll") for (int n = 0; n < 8; ++n)                               \
      _Pragma("unroll") for (int r = 0; r < 4; ++r)                               \
          tm = fmaxf(tm, sc[g2][n][r]);                                           \
      tm = fmaxf(tm, __shfl_xor(tm, 16));                                         \
      tm = fmaxf(tm, __shfl_xor(tm, 32));                                         \
      if (!__all(tm <= m_run[g2] + 44.0f)) {                                      \
        const float mnew = fmaxf(m_run[g2], tm);                                  \
        const float fac = exp2f((m_run[g2] - mnew) * Cs);                         \
        m_run[g2] = mnew;                                                         \
        l_run[g2] *= fac;                                                         \
        _Pragma("unroll") for (int m = 0; m < 4; ++m)                             \
        _Pragma("unroll") for (int r = 0; r < 4; ++r) acc[g2][m][r] *= fac;       \
      }                                                                           \
      float rs = 0.f;                                                             \
      const float mneg = -m_run[g2] * Cs;                                         \
      _Pragma("unroll") for (int n = 0; n < 8; ++n)                               \
      _Pragma("unroll") for (int r = 0; r < 4; ++r) {                             \
        const float p = exp2f(fmaf(sc[g2][n][r], Cs, mneg));                      \
        sc[g2][n][r] = p;                                                         \
        rs += p;                                                                  \
      }                                                                           \
      rs += __shfl_xor(rs, 16);                                                   \
      rs += __shfl_xor(rs, 32);                                                   \
      l_run[g2] += rs;                                                            \
      _Pragma("unroll") for (int n = 0; n < 8; ++n) {                             \
        asm("v_cvt_pk_bf16_f32 %0, %1, %2"                                        \
            : "=v"(pk[g2].u[2 * n]) : "v"(sc[g2][n][0]), "v"(sc[g2][n][1]));      \
        asm("v_cvt_pk_bf16_f32 %0, %1, %2"                                        \
            : "=v"(pk[g2].u[2 * n + 1]) : "v"(sc[g2][n][2]), "v"(sc[g2][n][3])); \
      }                                                                           \
    }                                                                             \
    _Pragma("unroll") for (int m = 0; m < 4; ++m) {                               \
      const u16* vr = vt + m * 2048;                                              \
      s16x8 vfr[4];                                                               \
      _Pragma("unroll") for (int c = 0; c < 4; ++c) {                             \
        union VF { s16x4 h[2]; s16x8 v; } vv;                                     \
        vv.h[0] = *reinterpret_cast<const s16x4*>(vr + vbase[2 * c]);             \
        vv.h[1] = *reinterpret_cast<const s16x4*>(vr + vbase[2 * c + 1]);         \
        vfr[c] = vv.v;                                                            \
      }                                                                           \
      __builtin_amdgcn_s_setprio(1);                                              \
      _Pragma("unroll") for (int c = 0; c < 4; ++c) {                             \
        acc[0][m] = MFMA16(vfr[c], pk[0].v[c], acc[0][m]);                        \
        acc[1][m] = MFMA16(vfr[c], pk[1].v[c], acc[1][m]);                        \
      }                                                                           \
      __builtin_amdgcn_s_setprio(0);                                              \
    }                                                                             \
    mcur0 = mnext0;                                                               \
    mcur1 = mnext1;                                                               \
  }

  for (int t = 0; t < NTT_; t += 2) {
    ATTN_TILE(t, 0)
    ATTN_TILE(t + 1, 1)
  }
#undef ATTN_TILE

  // normalize + store O^T -> O (bf16, token-major [BS][D])
#pragma unroll
  for (int g2 = 0; g2 < 2; ++g2) {
    const float rl = 1.0f / l_run[g2];
    u16* op = O + (size_t)(b * S_ + q0 + g2 * 16 + l16) * D_ + h * HD_ + kq * 4;
#pragma unroll
    for (int m = 0; m < 4; ++m) {
      uint2 o;
      o.x = (uint32_t)f2b(acc[g2][m][0] * rl) | ((uint32_t)f2b(acc[g2][m][1] * rl) << 16);
      o.y = (uint32_t)f2b(acc[g2][m][2] * rl) | ((uint32_t)f2b(acc[g2][m][3] * rl) << 16);
      *reinterpret_cast<uint2*>(op + m * 16) = o;
    }
  }
}

// ---------------- launch ----------------
extern "C" void kernel_launch(void* const* d_in, const int* in_sizes, int n_in,
                              void* d_out, int out_size, void* d_ws, size_t ws_size,
                              hipStream_t stream) {
  const float* x = (const float*)d_in[0];
  const int* mask = (const int*)d_in[1];
  const float* Wq = (const float*)d_in[2];
  const float* Wk = (const float*)d_in[3];
  const float* Wv = (const float*)d_in[4];
  const float* Wo = (const float*)d_in[5];

  char* w = (char*)d_ws;
  u16* xb = (u16*)w;    w += (size_t)BS_ * D_ * 2;     // contiguous cvt dst
  u16* Wqkvb = (u16*)w; w += (size_t)QKVS_ * D_ * 2;
  u16* Wob = (u16*)w;   w += (size_t)D_ * D_ * 2;
  u16* QKVw = (u16*)w;  w += (size_t)BS_ * QKVS_ * 2;
  u16* VTw = (u16*)w;   w += (size_t)B_ * KVH_ * HD_ * S_ * 2;
  u16* AOw = (u16*)w;   w += (size_t)BS_ * D_ * 2;

  const int n4tot = (BS_ * D_ + QKVS_ * D_ + D_ * D_) / 4;
  cvt5_kernel<<<dim3(2048), dim3(256), 0, stream>>>(x, Wq, Wk, Wv, Wo, xb, n4tot);

  // fused QKV projection (V cols written transposed to VTw): 768 blocks (3/CU)
  gemm64<1, 1><<<dim3(QKVS_ / 128, BS_ / 64), dim3(256), 0, stream>>>(
      xb, Wqkvb, QKVw, VTw, BS_, QKVS_, D_);
  // attention: (S/32, B*KVH) blocks of 4 waves, 32 q-rows/wave, KVBLK=128
  attn_kernel<<<dim3(S_ / 32, B_ * KVH_), dim3(256), 0, stream>>>(QKVw, VTw, mask, AOw);
  // output projection -> fp32 d_out, 512 blocks (dbuf staging)
  gemm64<0, 0><<<dim3(D_ / 128, BS_ / 64), dim3(256), 0, stream>>>(
      AOw, Wob, (float*)d_out, nullptr, BS_, D_, D_);
}

// Round 21
// 113.553 us; speedup vs baseline: 1.4123x; 1.0181x over previous
//
#include <hip/hip_runtime.h>
#include <hip/hip_bf16.h>
#include <stdint.h>

// Problem constants (GroupedQueryAttention: B=2,S=2048,D=1024,H=16,KVH=4)
#define B_    2
#define S_    2048
#define D_    1024
#define H_    16
#define KVH_  4
#define HD_   64
#define REP_  4
#define BS_   (B_ * S_)        // 4096 tokens
#define KVD_  256
#define QKVS_ 1536             // fused QKV row stride: Q(1024) | K(256) | V(256)
#define NTT_  (S_ / 128)       // 16 KV tiles of 128
#define VSPLIT_ (D_ + KVD_)    // 1280: V columns start here (block-aligned)

typedef unsigned short u16;
typedef short s16x4 __attribute__((ext_vector_type(4)));
typedef short s16x8 __attribute__((ext_vector_type(8)));
typedef float f32x4 __attribute__((ext_vector_type(4)));

typedef const __attribute__((address_space(1))) void* gvp;
typedef __attribute__((address_space(3))) void* lvp;

#define MFMA16(a, b, c) __builtin_amdgcn_mfma_f32_16x16x32_bf16((a), (b), (c), 0, 0, 0)

__device__ __forceinline__ u16 f2b(float f) {  // RNE f32->bf16 (finite inputs)
  uint32_t u = __float_as_uint(f);
  u += 0x7fffu + ((u >> 16) & 1u);
  return (u16)(u >> 16);
}

// XOR swizzles: 64-wide rows (8 x 16B slots) and 128-wide rows (16 slots).
__device__ __forceinline__ int swz64(int row, int slot) {
  return slot ^ (row & 7) ^ ((row >> 3) & 7);
}
__device__ __forceinline__ int swz128(int row, int slot) {
  return slot ^ (row & 15);
}

// ---------------- fused f32 -> bf16 conversion over 5 segments ----------------
#define N0_ (BS_ * D_ / 4)
#define N1_ (D_ * D_ / 4)
#define N2_ (KVD_ * D_ / 4)
__global__ void cvt5_kernel(const float* __restrict__ s0, const float* __restrict__ s1,
                            const float* __restrict__ s2, const float* __restrict__ s3,
                            const float* __restrict__ s4, u16* __restrict__ dst, int n4tot) {
  for (int i = blockIdx.x * blockDim.x + threadIdx.x; i < n4tot;
       i += gridDim.x * blockDim.x) {
    const float* src;
    int j = i;
    if (j < N0_) src = s0;
    else if ((j -= N0_) < N1_) src = s1;
    else if ((j -= N1_) < N2_) src = s2;
    else if ((j -= N2_) < N2_) src = s3;
    else { j -= N2_; src = s4; }
    const float4 v = reinterpret_cast<const float4*>(src)[j];
    uint2 o;
    o.x = (uint32_t)f2b(v.x) | ((uint32_t)f2b(v.y) << 16);
    o.y = (uint32_t)f2b(v.z) | ((uint32_t)f2b(v.w) << 16);
    reinterpret_cast<uint2*>(dst)[i] = o;
  }
}

// ---------------- bf16 GEMM, C = A(MxK) * B(NxK)^T, 64x128 tile, BK=64 ----------------
// Double-buffered staging; swz64 both-sides LDS swizzle; XCD-bijective grid.
// WRITE_VT: V-columns (>= VSPLIT_) written TRANSPOSED to VT (fused vtrans).
template <int OUT_BF16, int WRITE_VT>
__global__ __launch_bounds__(256) void gemm64(const u16* __restrict__ A,
                                              const u16* __restrict__ Bw,
                                              void* __restrict__ Cout,
                                              u16* __restrict__ VT,
                                              int M, int N, int K) {
  __shared__ u16 As[2][64 * 64];
  __shared__ u16 Bs[2][128 * 64];
  const int tid = threadIdx.x;
  const int lane = tid & 63;
  const int wid = tid >> 6;
  const int l16 = lane & 15;
  const int kq = lane >> 4;
  // XCD swizzle: hw-blocks on one XCD (bid0 mod 8) get a contiguous logical chunk
  const int nwg = gridDim.x * gridDim.y;
  const int bid0 = blockIdx.y * gridDim.x + blockIdx.x;
  const int bid = (bid0 & 7) * (nwg >> 3) + (bid0 >> 3);
  const int bm = (bid / gridDim.x) * 64;
  const int bn = (bid % gridDim.x) * 128;
  const int wr = (wid >> 1) * 32;
  const int wc = (wid & 1) * 64;

  // staging geometry (pre-swizzled source cols, linear LDS dst)
  int arow[2], acol[2], brow[4], bcol[4], sdst[4];
#pragma unroll
  for (int i = 0; i < 4; ++i) {
    const int e = (i * 256 + tid) * 8;
    const int row = e >> 6;
    const int col = swz64(row, (e >> 3) & 7) * 8;
    sdst[i] = e;
    if (i < 2) { arow[i] = row; acol[i] = col; }
    brow[i] = row;
    bcol[i] = col;
  }
  // frag read offsets (involution)
  int aoff[2][2], boff[4][2];
#pragma unroll
  for (int m = 0; m < 2; ++m)
#pragma unroll
    for (int kk = 0; kk < 2; ++kk) {
      const int row = wr + m * 16 + l16;
      aoff[m][kk] = row * 64 + swz64(row, kk * 4 + kq) * 8;
    }
#pragma unroll
  for (int n = 0; n < 4; ++n)
#pragma unroll
    for (int kk = 0; kk < 2; ++kk) {
      const int row = wc + n * 16 + l16;
      boff[n][kk] = row * 64 + swz64(row, kk * 4 + kq) * 8;
    }

  auto stage = [&](int buf, int kt) {
#pragma unroll
    for (int i = 0; i < 2; ++i)
      __builtin_amdgcn_global_load_lds((gvp)(A + (size_t)(bm + arow[i]) * K + kt + acol[i]),
                                       (lvp)(&As[buf][sdst[i]]), 16, 0, 0);
#pragma unroll
    for (int i = 0; i < 4; ++i)
      __builtin_amdgcn_global_load_lds((gvp)(Bw + (size_t)(bn + brow[i]) * K + kt + bcol[i]),
                                       (lvp)(&Bs[buf][sdst[i]]), 16, 0, 0);
  };

  f32x4 acc[2][4] = {};
  stage(0, 0);
  int cur = 0;

  for (int kt = 0; kt < K; kt += 64) {
    __syncthreads();                   // buf[cur] ready (drains in-flight loads)
    if (kt + 64 < K) stage(cur ^ 1, kt + 64);

#pragma unroll
    for (int kk = 0; kk < 2; ++kk) {
      s16x8 af[2], bfr[4];
#pragma unroll
      for (int m = 0; m < 2; ++m)
        af[m] = *reinterpret_cast<const s16x8*>(&As[cur][aoff[m][kk]]);
#pragma unroll
      for (int n = 0; n < 4; ++n)
        bfr[n] = *reinterpret_cast<const s16x8*>(&Bs[cur][boff[n][kk]]);
#pragma unroll
      for (int m = 0; m < 2; ++m)
#pragma unroll
        for (int n = 0; n < 4; ++n)
          acc[m][n] = MFMA16(af[m], bfr[n], acc[m][n]);
    }
    cur ^= 1;
  }

  if (WRITE_VT && bn >= VSPLIT_) {
    // V block: write transposed to VT[((b*4+g)*64+d)][s]; 4 consecutive tokens
    // per (m,n) = 8B contiguous store.
#pragma unroll
    for (int m = 0; m < 2; ++m) {
      const int row0 = bm + wr + m * 16 + kq * 4;   // token row (4 consecutive)
      const int b = row0 >> 11;
      const int s = row0 & (S_ - 1);
#pragma unroll
      for (int n = 0; n < 4; ++n) {
        const int off = bn - VSPLIT_ + wc + n * 16 + l16;
        const int g = off >> 6;
        const int d = off & 63;
        uint2 o;
        o.x = (uint32_t)f2b(acc[m][n][0]) | ((uint32_t)f2b(acc[m][n][1]) << 16);
        o.y = (uint32_t)f2b(acc[m][n][2]) | ((uint32_t)f2b(acc[m][n][3]) << 16);
        *reinterpret_cast<uint2*>(&VT[((size_t)(b * 4 + g) * 64 + d) * S_ + s]) = o;
      }
    }
    return;
  }

#pragma unroll
  for (int m = 0; m < 2; ++m) {
    const int row0 = bm + wr + m * 16 + kq * 4;
#pragma unroll
    for (int n = 0; n < 4; ++n) {
      const int col = bn + wc + n * 16 + l16;
#pragma unroll
      for (int r = 0; r < 4; ++r) {
        if (OUT_BF16) {
          ((u16*)Cout)[(size_t)(row0 + r) * N + col] = f2b(acc[m][n][r]);
        } else {
          ((float*)Cout)[(size_t)(row0 + r) * N + col] = acc[m][n][r];
        }
      }
    }
  }
}

// ---------------- flash attention (GQA): zero-shuffle PV, KVBLK=128 ----------------
// Softmax reductions TREE-structured (4 independent per-r chains, depth 8)
// to break the former 32-deep serial fmax/add dependency chains.
__global__ __launch_bounds__(256, 2) void attn_kernel(const u16* __restrict__ QKV,
                                                      const u16* __restrict__ VT,
                                                      const int* __restrict__ mask,
                                                      u16* __restrict__ O) {
  __shared__ u16 Ks[2][128 * 64];      // K rows, 64-wide swizzled
  __shared__ u16 Vt[2][64 * 128];      // V^T rows (d), 128-wide swizzled

  const int tid = threadIdx.x;
  const int lane = tid & 63;
  const int wid = tid >> 6;            // 0..3 = head within group
  const int l16 = lane & 15;
  const int kq = lane >> 4;            // 0..3
  const int bg = blockIdx.y;
  const int b = bg >> 2;               // / KVH
  const int g = bg & 3;
  const int h = g * REP_ + wid;
  const int q0 = blockIdx.x * 32;
  const u16* kv_base = QKV + (size_t)b * S_ * QKVS_ + D_ + g * HD_;  // K cols
  const u16* vt_base = VT + (size_t)bg * 64 * S_;                     // V^T rows
  const int* maskp = mask + b * S_ + lane;
  const float Cs = 0.18033688011112042f;  // SCALE * log2(e)

  // ---- precomputed per-thread LDS element offsets (loop-invariant) ----
  int koff[8][2];
#pragma unroll
  for (int n = 0; n < 8; ++n)
#pragma unroll
    for (int c = 0; c < 2; ++c) {
      const int row = n * 16 + l16;
      koff[n][c] = row * 64 + swz64(row, c * 4 + kq) * 8;
    }
  const int hs = kq >> 1;
  const int bo = 4 * (kq & 1);
  int vbase[8];                        // voff = vbase[j] + m*2048  (drow&15 == l16)
#pragma unroll
  for (int c = 0; c < 4; ++c) {
    vbase[2 * c] = l16 * 128 + swz128(l16, 4 * c + hs) * 8 + bo;
    vbase[2 * c + 1] = l16 * 128 + swz128(l16, 4 * c + 2 + hs) * 8 + bo;
  }
  int kst_src[4], vst_src[4], st_dst[4];
#pragma unroll
  for (int i = 0; i < 4; ++i) {
    const int e = (i * 256 + tid) * 8;
    st_dst[i] = e;
    const int krow = e >> 6;
    kst_src[i] = krow * QKVS_ + swz64(krow, (e >> 3) & 7) * 8;   // + kv0*QKVS_
    const int vrow = e >> 7;
    vst_src[i] = vrow * S_ + swz128(vrow, (e >> 3) & 15) * 8;    // + kv0
  }

  auto kstage = [&](int buf, int kv0) {
#pragma unroll
    for (int i = 0; i < 4; ++i)
      __builtin_amdgcn_global_load_lds(
          (gvp)(kv_base + (size_t)kv0 * QKVS_ + kst_src[i]),
          (lvp)(&Ks[buf][st_dst[i]]), 16, 0, 0);
  };
  auto vstage = [&](int buf, int kv0) {
#pragma unroll
    for (int i = 0; i < 4; ++i)
      __builtin_amdgcn_global_load_lds(
          (gvp)(vt_base + kv0 + vst_src[i]),
          (lvp)(&Vt[buf][st_dst[i]]), 16, 0, 0);
  };

  // Q B-frags: qf[g2][c] = Q[q0+g2*16+l16][c*32+kq*8..]
  s16x8 qf[2][2];
#pragma unroll
  for (int g2 = 0; g2 < 2; ++g2) {
    const u16* qp = QKV + (size_t)(b * S_ + q0 + g2 * 16 + l16) * QKVS_ + h * HD_ + kq * 8;
    qf[g2][0] = *reinterpret_cast<const s16x8*>(qp);
    qf[g2][1] = *reinterpret_cast<const s16x8*>(qp + 32);
  }

  // prologue: stage tile 0 into buf 0; mask tile 0 into regs
  kstage(0, 0);
  vstage(0, 0);
  int mcur0 = maskp[0];
  int mcur1 = maskp[64];

  float m_run[2] = {-1e30f, -1e30f}, l_run[2] = {0.f, 0.f};
  f32x4 acc[2][4] = {};                // O^T per group: row d=m*16+kq*4+r, col q=l16

#define ATTN_TILE(T_, BUF_)                                                       \
  {                                                                               \
    const int t_ = (T_);                                                          \
    __syncthreads();                                                              \
    const bool pfch = (t_ + 1 < NTT_);                                            \
    int mnext0 = 0, mnext1 = 0;                                                   \
    if (pfch) {                                                                   \
      kstage((BUF_) ^ 1, (t_ + 1) * 128);                                         \
      vstage((BUF_) ^ 1, (t_ + 1) * 128);                                         \
      mnext0 = maskp[(t_ + 1) * 128];                                             \
      mnext1 = maskp[(t_ + 1) * 128 + 64];                                        \
    }                                                                             \
    const u16* ks = &Ks[(BUF_)][0];                                               \
    const u16* vt = &Vt[(BUF_)][0];                                               \
    f32x4 sc[2][8];                                                               \
    __builtin_amdgcn_s_setprio(1);                                                \
    _Pragma("unroll") for (int n = 0; n < 8; ++n) {                               \
      const s16x8 kf0 = *reinterpret_cast<const s16x8*>(ks + koff[n][0]);         \
      const s16x8 kf1 = *reinterpret_cast<const s16x8*>(ks + koff[n][1]);         \
      f32x4 s0 = {0.f, 0.f, 0.f, 0.f};                                            \
      f32x4 s1 = {0.f, 0.f, 0.f, 0.f};                                            \
      s0 = MFMA16(kf0, qf[0][0], s0);                                             \
      s1 = MFMA16(kf0, qf[1][0], s1);                                             \
      s0 = MFMA16(kf1, qf[0][1], s0);                                             \
      s1 = MFMA16(kf1, qf[1][1], s1);                                             \
      sc[0][n] = s0;                                                              \
      sc[1][n] = s1;                                                              \
    }                                                                             \
    __builtin_amdgcn_s_setprio(0);                                                \
    const unsigned long long mb0 = __ballot(mcur0 != 0);                          \
    const unsigned long long mb1 = __ballot(mcur1 != 0);                          \
    if ((~mb0) | (~mb1)) {                                                        \
      _Pragma("unroll") for (int n = 0; n < 8; ++n) {                             \
        const unsigned long long mb = (n < 4) ? mb0 : mb1;                        \
        const int sh = (n & 3) * 16 + kq * 4;                                     \
        _Pragma("unroll") for (int r = 0; r < 4; ++r) {                           \
          if (!((mb >> (sh + r)) & 1ull)) {                                       \
            sc[0][n][r] = -3.0e38f;                                               \
            sc[1][n][r] = -3.0e38f;                                               \
          }                                                                       \
        }                                                                         \
      }                                                                           \
    }                                                                             \
    union PK { uint32_t u[16]; s16x8 v[4]; } pk[2];                               \
    _Pragma("unroll") for (int g2 = 0; g2 < 2; ++g2) {                            \
      f32x4 tv = sc[g2][0];                                                       \
      _Pragma("unroll") for (int n = 1; n < 8; ++n) {                             \
        tv[0] = fmaxf(tv[0], sc[g2][n][0]);                                       \
        tv[1] = fmaxf(tv[1], sc[g2][n][1]);                                       \
        tv[2] = fmaxf(tv[2], sc[g2][n][2]);                                       \
        tv[3] = fmaxf(tv[3], sc[g2][n][3]);                                       \
      }                                                                           \
      float tm = fmaxf(fmaxf(tv[0], tv[1]), fmaxf(tv[2], tv[3]));                 \
      tm = fmaxf(tm, __shfl_xor(tm, 16));                                         \
      tm = fmaxf(tm, __shfl_xor(tm, 32));                                         \
      if (!__all(tm <= m_run[g2] + 44.0f)) {                                      \
        const float mnew = fmaxf(m_run[g2], tm);                                  \
        const float fac = exp2f((m_run[g2] - mnew) * Cs);                         \
        m_run[g2] = mnew;                                                         \
        l_run[g2] *= fac;                                                         \
        _Pragma("unroll") for (int m = 0; m < 4; ++m)                             \
        _Pragma("unroll") for (int r = 0; r < 4; ++r) acc[g2][m][r] *= fac;       \
      }                                                                           \
      f32x4 rsv = {0.f, 0.f, 0.f, 0.f};                                           \
      const float mneg = -m_run[g2] * Cs;                                         \
      _Pragma("unroll") for (int n = 0; n < 8; ++n)                               \
      _Pragma("unroll") for (int r = 0; r < 4; ++r) {                             \
        const float p = exp2f(fmaf(sc[g2][n][r], Cs, mneg));                      \
        sc[g2][n][r] = p;                                                         \
        rsv[r] += p;                                                              \
      }                                                                           \
      float rs = (rsv[0] + rsv[1]) + (rsv[2] + rsv[3]);                           \
      rs += __shfl_xor(rs, 16);                                                   \
      rs += __shfl_xor(rs, 32);                                                   \
      l_run[g2] += rs;                                                            \
      _Pragma("unroll") for (int n = 0; n < 8; ++n) {                             \
        asm("v_cvt_pk_bf16_f32 %0, %1, %2"                                        \
            : "=v"(pk[g2].u[2 * n]) : "v"(sc[g2][n][0]), "v"(sc[g2][n][1]));      \
        asm("v_cvt_pk_bf16_f32 %0, %1, %2"                                        \
            : "=v"(pk[g2].u[2 * n + 1]) : "v"(sc[g2][n][2]), "v"(sc[g2][n][3])); \
      }                                                                           \
    }                                                                             \
    _Pragma("unroll") for (int m = 0; m < 4; ++m) {                               \
      const u16* vr = vt + m * 2048;                                              \
      s16x8 vfr[4];                                                               \
      _Pragma("unroll") for (int c = 0; c < 4; ++c) {                             \
        union VF { s16x4 h[2]; s16x8 v; } vv;                                     \
        vv.h[0] = *reinterpret_cast<const s16x4*>(vr + vbase[2 * c]);             \
        vv.h[1] = *reinterpret_cast<const s16x4*>(vr + vbase[2 * c + 1]);         \
        vfr[c] = vv.v;                                                            \
      }                                                                           \
      __builtin_amdgcn_s_setprio(1);                                              \
      _Pragma("unroll") for (int c = 0; c < 4; ++c) {                             \
        acc[0][m] = MFMA16(vfr[c], pk[0].v[c], acc[0][m]);                        \
        acc[1][m] = MFMA16(vfr[c], pk[1].v[c], acc[1][m]);                        \
      }                                                                           \
      __builtin_amdgcn_s_setprio(0);                                              \
    }                                                                             \
    mcur0 = mnext0;                                                               \
    mcur1 = mnext1;                                                               \
  }

  for (int t = 0; t < NTT_; t += 2) {
    ATTN_TILE(t, 0)
    ATTN_TILE(t + 1, 1)
  }
#undef ATTN_TILE

  // normalize + store O^T -> O (bf16, token-major [BS][D])
#pragma unroll
  for (int g2 = 0; g2 < 2; ++g2) {
    const float rl = 1.0f / l_run[g2];
    u16* op = O + (size_t)(b * S_ + q0 + g2 * 16 + l16) * D_ + h * HD_ + kq * 4;
#pragma unroll
    for (int m = 0; m < 4; ++m) {
      uint2 o;
      o.x = (uint32_t)f2b(acc[g2][m][0] * rl) | ((uint32_t)f2b(acc[g2][m][1] * rl) << 16);
      o.y = (uint32_t)f2b(acc[g2][m][2] * rl) | ((uint32_t)f2b(acc[g2][m][3] * rl) << 16);
      *reinterpret_cast<uint2*>(op + m * 16) = o;
    }
  }
}

// ---------------- launch ----------------
extern "C" void kernel_launch(void* const* d_in, const int* in_sizes, int n_in,
                              void* d_out, int out_size, void* d_ws, size_t ws_size,
                              hipStream_t stream) {
  const float* x = (const float*)d_in[0];
  const int* mask = (const int*)d_in[1];
  const float* Wq = (const float*)d_in[2];
  const float* Wk = (const float*)d_in[3];
  const float* Wv = (const float*)d_in[4];
  const float* Wo = (const float*)d_in[5];

  char* w = (char*)d_ws;
  u16* xb = (u16*)w;    w += (size_t)BS_ * D_ * 2;     // contiguous cvt dst
  u16* Wqkvb = (u16*)w; w += (size_t)QKVS_ * D_ * 2;
  u16* Wob = (u16*)w;   w += (size_t)D_ * D_ * 2;
  u16* QKVw = (u16*)w;  w += (size_t)BS_ * QKVS_ * 2;
  u16* VTw = (u16*)w;   w += (size_t)B_ * KVH_ * HD_ * S_ * 2;
  u16* AOw = (u16*)w;   w += (size_t)BS_ * D_ * 2;

  const int n4tot = (BS_ * D_ + QKVS_ * D_ + D_ * D_) / 4;
  cvt5_kernel<<<dim3(2048), dim3(256), 0, stream>>>(x, Wq, Wk, Wv, Wo, xb, n4tot);

  // fused QKV projection (V cols written transposed to VTw): 768 blocks (3/CU)
  gemm64<1, 1><<<dim3(QKVS_ / 128, BS_ / 64), dim3(256), 0, stream>>>(
      xb, Wqkvb, QKVw, VTw, BS_, QKVS_, D_);
  // attention: (S/32, B*KVH) blocks of 4 waves, 32 q-rows/wave, KVBLK=128
  attn_kernel<<<dim3(S_ / 32, B_ * KVH_), dim3(256), 0, stream>>>(QKVw, VTw, mask, AOw);
  // output projection -> fp32 d_out, 512 blocks (dbuf staging)
  gemm64<0, 0><<<dim3(D_ / 128, BS_ / 64), dim3(256), 0, stream>>>(
      AOw, Wob, (float*)d_out, nullptr, BS_, D_, D_);
}